// Round 9
// baseline (34.243 us; speedup 1.0000x reference)
//
#include <hip/hip_runtime.h>
#include <hip/hip_fp16.h>
#include <cmath>

// Match XLA/numpy: no FMA contraction anywhere (a*b - c*d must be two ops).
#pragma clang fp contract(off)

#define MAXK 2048  // next pow2 >= K (K=2000)

struct TriUV {
  float u0x, u0y, u1x, u1y;
  float u2x, u2y, pad0, pad1;
};

// All per-visit tri data in ONE 128B cache line (128-aligned).
struct __align__(128) TriRec {
  uint4 ap;     // fp16 edge coeffs packed
  float4 mt;    // M, fC, orig-as-float, 0
  float4 q0;    // t1x,t1y,dAy,dAx
  float4 q1;    // t2x,t2y,dBy,dBx
  float4 q2;    // t0x,t0y,dCy,dCx
  float4 q3;    // z0,z1,z2,w
  float4 pad0, pad1;  // -> 128B
};

__device__ __forceinline__ float h2f(unsigned v) {
  __half_raw r; r.x = (unsigned short)v;
  return __half2float(__half(r));
}
__device__ __forceinline__ unsigned f2h(float v) {
  return (unsigned)__half_as_ushort(__float2half(v));
}
__device__ __forceinline__ unsigned pkh(float lo, float hi) {
  return f2h(lo) | (f2h(hi) << 16);
}
// order-preserving float<->uint map (monotone for all finite floats)
__device__ __forceinline__ unsigned fmapu(float f) {
  unsigned b = __float_as_uint(f);
  return (b & 0x80000000u) ? ~b : (b | 0x80000000u);
}
__device__ __forceinline__ float funmap(unsigned m) {
  return __uint_as_float((m & 0x80000000u) ? (m ^ 0x80000000u) : ~m);
}

// jnp.linspace(-1, 1, n): start*(1-step) + stop*step with step=i/(n-1),
// endpoint concatenated exactly.
__device__ __forceinline__ float lin_at(int i, int n) {
#pragma clang fp contract(off)
  if (i == n - 1) return 1.0f;
  float step = (float)i / (float)(n - 1);
  return (-1.0f) * (1.0f - step) + 1.0f * step;
}

// PARALLEL single-pass prep with VALID-TRI COMPACTION: valid tris get a
// slot from a global atomic counter (order nondeterministic — safe because
// the winner is the order-independent lex-max of (z, orig), orig carried in
// the key; slotOf[orig] maps back for the epilogue). Invalid tris write
// nothing. Block 0: minz reduction. Blocks 1..: 256 tris each.
__global__ __launch_bounds__(256) void prep_kernel(
    const float* __restrict__ verts, const int* __restrict__ faces,
    const float* __restrict__ uv, const int* __restrict__ uvfaces, int V, int K,
    TriRec* __restrict__ rec, float4* __restrict__ bboxS,
    float4* __restrict__ planeS, int* __restrict__ slotOf,
    TriUV* __restrict__ tuv, float* __restrict__ zinit,
    int* __restrict__ counter) {
#pragma clang fp contract(off)
  __shared__ float smz[256];
  int tid = (int)threadIdx.x;
  int bid = (int)blockIdx.x;
  if (bid == 0) {
    float m = 3.402823466e38f;
    for (int i = tid; i < V; i += 256) m = fminf(m, verts[3 * i + 2]);
    smz[tid] = m;
    __syncthreads();
    for (int s2 = 128; s2 > 0; s2 >>= 1) {
      if (tid < s2) smz[tid] = fminf(smz[tid], smz[tid + s2]);
      __syncthreads();
    }
    if (tid == 0) *zinit = smz[0];
    return;
  }
  int t = (bid - 1) * 256 + tid;
  if (t >= K) return;
  int i0 = faces[3 * t + 0], i1 = faces[3 * t + 1], i2 = faces[3 * t + 2];
  float t0x = verts[3 * i0 + 0], t0y = verts[3 * i0 + 1], z0 = verts[3 * i0 + 2];
  float t1x = verts[3 * i1 + 0], t1y = verts[3 * i1 + 1], z1 = verts[3 * i1 + 2];
  float t2x = verts[3 * i2 + 0], t2y = verts[3 * i2 + 1], z2 = verts[3 * i2 + 2];
  int j0 = uvfaces[3 * t + 0], j1 = uvfaces[3 * t + 1], j2 = uvfaces[3 * t + 2];
  TriUV u;
  u.u0x = uv[2 * j0 + 0] * 2.0f - 1.0f;
  u.u0y = uv[2 * j0 + 1] * 2.0f - 1.0f;
  u.u1x = uv[2 * j1 + 0] * 2.0f - 1.0f;
  u.u1y = uv[2 * j1 + 1] * 2.0f - 1.0f;
  u.u2x = uv[2 * j2 + 0] * 2.0f - 1.0f;
  u.u2y = uv[2 * j2 + 1] * 2.0f - 1.0f;
  u.pad0 = 0.0f; u.pad1 = 0.0f;
  tuv[t] = u;
  // w == normal_z bitwise: valid & (w>=EPS) <=> w >= 1e-9f
  float w = (t1x - t0x) * (t2y - t0y) - (t1y - t0y) * (t2x - t0x);
  if (w < 1e-9f) return;  // compacted out — render never sees it
  int slot = atomicAdd(counter, 1);
  slotOf[t] = slot;
  float dAy = t0y - t1y, dAx = t0x - t1x;  // edge A (pAB), anchor t1
  float dBy = t1y - t2y, dBx = t1x - t2x;  // edge B (pCB), anchor t2
  float dCy = t2y - t0y, dCx = t2x - t0x;  // edge C (pCA), anchor t0
  bboxS[slot] = make_float4(fminf(fminf(t0x, t1x), t2x),
                            fmaxf(fmaxf(t0x, t1x), t2x),
                            fminf(fminf(t0y, t1y), t2y),
                            fmaxf(fmaxf(t0y, t1y), t2y));
  // Approx edge form: p ~= px*d - py*e + f, f = b*e - a*d (anchor (a,b)).
  float fA = t1y * dAx - t1x * dAy;
  float fB = t2y * dBx - t2x * dBy;
  float fC = t0y * dCx - t0x * dCy;
  // Sound margin: fp16 quantization + fp32 fma + exact-expr rounding.
  float sA = fabsf(dAy) + fabsf(dAx) + fabsf(fA);
  float sB = fabsf(dBy) + fabsf(dBx) + fabsf(fB);
  float sC = fabsf(dCy) + fabsf(dCx) + fabsf(fC);
  float M = fmaxf(fmaxf(sA, sB), sC) * 9.766e-4f + 1e-4f;
  TriRec r;
  r.ap = make_uint4(pkh(dAy, dAx), pkh(fA, dBy), pkh(dBx, fB), pkh(dCy, dCx));
  r.mt = make_float4(M, fC, __int_as_float(t), 0.0f);  // orig in mt.z
  r.q0 = make_float4(t1x, t1y, dAy, dAx);
  r.q1 = make_float4(t2x, t2y, dBy, dBx);
  r.q2 = make_float4(t0x, t0y, dCy, dCx);
  r.q3 = make_float4(z0, z1, z2, w);
  r.pad0 = make_float4(0.f, 0.f, 0.f, 0.f);
  r.pad1 = make_float4(0.f, 0.f, 0.f, 0.f);
  rec[slot] = r;
  // z plane: z(x,y) = (z0*pCB + z1*pCA + z2*pAB)/w is affine in (x,y).
  // pXX(0,0) = fB/fC/fA; d(pCB)/dx = dBy, d(pCA)/dx = dCy, d(pAB)/dx = dAy.
  float zmx = fmaxf(fmaxf(z0, z1), z2);
  float gatef = zmx + 1e-3f + 1e-4f / w;  // exact global gate (strict UB)
  float gx = (z0 * dBy + z1 * dCy + z2 * dAy) / w;
  float gy = -(z0 * dBx + z1 * dCx + z2 * dAx) / w;
  float cc = (z0 * fB + z1 * fC + z2 * fA) / w;
  // margin: coefficient fp error (magnitude-scaled) + render-side eval
  // rounding + established inner-z error (1e-3 + 1e-4/w) + abs cushion.
  float mm = (fabsf(z0 * fB) + fabsf(z1 * fC) + fabsf(z2 * fA) +
              fabsf(z0 * dBy) + fabsf(z1 * dCy) + fabsf(z2 * dAy) +
              fabsf(z0 * dBx) + fabsf(z1 * dCx) + fabsf(z2 * dAx)) *
                 (2e-6f / w) +
             1e-3f + 1e-4f / w + 1e-4f;
  planeS[slot] = make_float4(gx, gy, cc + mm, gatef);
}

// 16x16 tile, 1024 threads = 16 waves (R6 structure — best measured).
// Wave wv: substream s=wv>>2 (parity-4 of the per-tile-gate-sorted list),
// quadrant q=wv&3 (lane ln -> pixel q*64+ln). Per-pixel winner = 64-bit LDS
// atomicMax of (map(z)<<32 | orig+1): exact lex-max of (z, orig); its HIGH
// WORD doubles as the pruning z-max (no separate s_zu).
// Phase 0 sorts bbox-survivors (compacted valid tris only) by
// tg = min(globalGate, planeZmaxOverTile + margin).
// Phase 1: scalar scan; per iteration ONE ds_read_b128 (em,tg,slot) + one
// b32 zb read; per deep visit ONE 128B cache line (TriRec).
__global__ __launch_bounds__(1024) void render_kernel(
    const TriRec* __restrict__ rec, const float4* __restrict__ bboxS,
    const float4* __restrict__ planeS, const int* __restrict__ countp,
    const int* __restrict__ slotOf, const TriUV* __restrict__ tuv,
    const float* __restrict__ zinitp, const float* __restrict__ uvmap, int T,
    float* __restrict__ out, int S) {
#pragma clang fp contract(off)
  __shared__ uint4 s_g[MAXK];                   // 32KB (em, tg, slot, 0)
  __shared__ unsigned long long s_key[256];     // 2KB winner (z,orig+1)
  __shared__ unsigned s_hist[256];              // 1KB
  __shared__ int s_cur[256];                    // 1KB
  __shared__ unsigned s_wsum[4];                // -> ~36KB total

  int tid = (int)threadIdx.x;
  int wv = tid >> 6, ln = tid & 63;
  int s = wv >> 2, q = wv & 3;
  int pix = (q << 6) + ln;
  int tilesX = S >> 4;
  int tileX = (int)blockIdx.x % tilesX;
  int tileY = (int)blockIdx.x / tilesX;
  int j = (tileX << 4) + (pix & 15);
  int i = (tileY << 4) + (pix >> 4);
  // pts[i][j] = (lin[j], lin[S-1-i])  (rot90 of meshgrid)
  float px = lin_at(j, S);
  float py = lin_at(S - 1 - i, S);
  float pxlo = lin_at(tileX << 4, S);
  float pxhi = lin_at((tileX << 4) + 15, S);
  float pylo = lin_at(S - 1 - ((tileY << 4) + 15), S);
  float pyhi = lin_at(S - 1 - (tileY << 4), S);

  int N = *countp;  // compacted valid-tri count
  float zinit = *zinitp;
  unsigned zinit_m = fmapu(zinit);
  if (tid < 256) {
    s_key[tid] = ((unsigned long long)zinit_m << 32);  // orig+1 = 0 -> none
    s_hist[tid] = 0u;
  }
  volatile unsigned* vhk = (volatile unsigned*)s_key;  // [2*pix+1] = high word
  __syncthreads();

  // ---- Phase 0: bbox cull + per-tile gate + 256-bucket counting sort ----
  bool kA = false, kB = false;
  int bA = 0, bB = 0;
  unsigned gA = 0, gB = 0;
  {
    int t = tid;
    if (t < N) {
      float4 bb = bboxS[t];  // xmin,xmax,ymin,ymax
      if (bb.x <= pxhi && bb.y >= pxlo && bb.z <= pyhi && bb.w >= pylo) {
        float4 pl = planeS[t];  // gx, gy, c+margin, globalGate
        float ub = pl.z + fmaxf(pl.x * pxlo, pl.x * pxhi) +
                   fmaxf(pl.y * pylo, pl.y * pyhi);
        float tg = fminf(pl.w, ub);
        kA = true;
        bA = min(max((int)((4.0f - tg) * 32.0f), 0), 255);
        gA = fmapu(tg);
      }
    }
    t = tid + 1024;
    if (t < N) {
      float4 bb = bboxS[t];
      if (bb.x <= pxhi && bb.y >= pxlo && bb.z <= pyhi && bb.w >= pylo) {
        float4 pl = planeS[t];
        float ub = pl.z + fmaxf(pl.x * pxlo, pl.x * pxhi) +
                   fmaxf(pl.y * pylo, pl.y * pyhi);
        float tg = fminf(pl.w, ub);
        kB = true;
        bB = min(max((int)((4.0f - tg) * 32.0f), 0), 255);
        gB = fmapu(tg);
      }
    }
  }
  if (kA) atomicAdd(&s_hist[bA], 1u);
  if (kB) atomicAdd(&s_hist[bB], 1u);
  __syncthreads();
  // 256-bin inclusive scan: 4 waves shuffle-scan 64 bins each + fixup.
  unsigned hx = 0, hinc = 0;
  if (tid < 256) {
    hx = s_hist[tid];
    unsigned v = hx;
#pragma unroll
    for (int d = 1; d < 64; d <<= 1) {
      unsigned tv = __shfl_up(v, d, 64);
      if (ln >= d) v += tv;
    }
    if (ln == 63) s_wsum[wv] = v;
    hinc = v;
  }
  __syncthreads();
  if (tid < 256) {
    unsigned add = 0;
    for (int w2 = 0; w2 < wv; ++w2) add += s_wsum[w2];
    hinc += add;
    s_hist[tid] = hinc;                 // inclusive totals (nk at bin 255)
    s_cur[tid] = (int)(hinc - hx);      // exclusive start cursor
  }
  __syncthreads();
  int nk = (int)s_hist[255];
  if (kA) {
    int sl = atomicAdd(&s_cur[bA], 1);
    float ef = (bA == 0) ? 3.402823466e38f : (4.0f - (float)bA * 0.03125f);
    s_g[sl] = make_uint4(fmapu(ef), gA, (unsigned)tid, 0u);
  }
  if (kB) {
    int sl = atomicAdd(&s_cur[bB], 1);
    float ef = (bB == 0) ? 3.402823466e38f : (4.0f - (float)bB * 0.03125f);
    s_g[sl] = make_uint4(fmapu(ef), gB, (unsigned)(tid + 1024), 0u);
  }
  __syncthreads();

  // ---- Phase 1: scalar parity-4 scan, continuous shared-z pruning ----
  for (int a = s; a < nk; a += 4) {
    uint4 g = s_g[a];               // one ds_read_b128: em, tg, slot
    unsigned zb = vhk[(pix << 1) + 1];  // fresh winner-key high word
    // edges monotone along substream: all lanes provably finished -> stop
    if (__all(g.x < zb)) break;
    if (g.y >= zb) {  // provable-skip pretest (tg>=zb implies em>=zb)
      const TriRec* r = &rec[g.z];  // whole visit = one 128B line
      uint4 ap = r->ap;
      float4 mt = r->mt;
      float M = mt.x, fC = mt.y;
      // approx edges (fp16 coeffs, fp32 fma); |approx-exact| <= M
      float aA = fmaf(px, h2f(ap.x & 0xffffu),
                      fmaf(-py, h2f(ap.x >> 16), h2f(ap.y & 0xffffu)));
      float aB = fmaf(px, h2f(ap.y >> 16),
                      fmaf(-py, h2f(ap.z & 0xffffu), h2f(ap.z >> 16)));
      float aC = fmaf(px, h2f(ap.w & 0xffffu),
                      fmaf(-py, h2f(ap.w >> 16), fC));
      if (fminf(fminf(aA, aB), aC) > -M) {  // not provably outside
        float4 q0 = r->q0, q1 = r->q1, q2 = r->q2;
        float pAB = (px - q0.x) * q0.z - (py - q0.y) * q0.w;
        float pCB = (px - q1.x) * q1.z - (py - q1.y) * q1.w;
        float pCA = (px - q2.x) * q2.z - (py - q2.y) * q2.w;
        if (pAB > 0.0f && pCB > 0.0f && pCA > 0.0f) {
          float4 q3 = r->q3;
          float w = q3.w;
          // scaled z pregate vs iteration-start zb (stale = conservative:
          // passes a superset; exact div path + atomicMax decide winner)
          float bzf = funmap(zb);
          float zs = (pCB * q3.x + pCA * q3.y) + ((w - pCB) - pCA) * q3.z;
          if (w < 1e-3f || zs >= (bzf - 1e-3f) * w) {
            float w1 = pCB / w;  // IEEE div, bitwise == reference
            float w2 = pCA / w;
            float w3 = (1.0f - w1) - w2;
            float z = (w1 * q3.x + w2 * q3.y) + w3 * q3.z;
            int o = __float_as_int(mt.z);  // ORIGINAL tri index
            unsigned zm = fmapu(z);
            unsigned long long key =
                ((unsigned long long)zm << 32) | (unsigned)(o + 1);
            atomicMax(&s_key[pix], key);
          }
        }
      }
    }
  }
  __syncthreads();

  // ---- Epilogue (tid<256, pix==tid): unpack winner, recompute w1/w2 ----
  if (tid < 256) {
    unsigned long long key = s_key[tid];
    unsigned oP1 = (unsigned)(key & 0xFFFFFFFFULL);
    float o0 = 0.0f, o1 = 0.0f, o2 = 0.0f, o3 = 0.0f;
    if (oP1 != 0) {
      int o = (int)oP1 - 1;       // original tri index
      int slot = slotOf[o];       // compacted slot
      const TriRec* r = &rec[slot];
      float4 q1 = r->q1, q2 = r->q2, q3 = r->q3;
      float pCB = (px - q1.x) * q1.z - (py - q1.y) * q1.w;
      float pCA = (px - q2.x) * q2.z - (py - q2.y) * q2.w;
      float w1 = pCB / q3.w;  // bitwise == inner-loop values
      float w2 = pCA / q3.w;
      float w3 = (1.0f - w1) - w2;
      TriUV u = tuv[o];
      float x = (w1 * u.u0x + w2 * u.u1x) + w3 * u.u2x;
      float y = (w1 * u.u0y + w2 * u.u1y) + w3 * u.u2y;
      float WH = (float)(T - 1);
      float fx = ((x + 1.0f) * WH) * 0.5f;
      float fy = ((y + 1.0f) * WH) * 0.5f;
      float ix0 = floorf(fx), iy0 = floorf(fy);
      float ix1 = ix0 + 1.0f, iy1 = iy0 + 1.0f;
      float wx1 = fx - ix0, wx0 = 1.0f - wx1;
      float wy1 = fy - iy0, wy0 = 1.0f - wy1;
      float w00 = wy0 * wx0, w01 = wy0 * wx1;
      float w10 = wy1 * wx0, w11 = wy1 * wx1;
      bool bx0 = (ix0 >= 0.0f) && (ix0 <= WH);
      bool bx1 = (ix1 >= 0.0f) && (ix1 <= WH);
      bool by0 = (iy0 >= 0.0f) && (iy0 <= WH);
      bool by1 = (iy1 >= 0.0f) && (iy1 <= WH);
      float m00 = (by0 && bx0) ? 1.0f : 0.0f;
      float m01 = (by0 && bx1) ? 1.0f : 0.0f;
      float m10 = (by1 && bx0) ? 1.0f : 0.0f;
      float m11 = (by1 && bx1) ? 1.0f : 0.0f;
      int cx0 = (int)fminf(fmaxf(ix0, 0.0f), WH);
      int cx1 = (int)fminf(fmaxf(ix1, 0.0f), WH);
      int cy0 = (int)fminf(fmaxf(iy0, 0.0f), WH);
      int cy1 = (int)fminf(fmaxf(iy1, 0.0f), WH);
      int TT = T * T;
      int i00 = cy0 * T + cx0, i01 = cy0 * T + cx1;
      int i10 = cy1 * T + cx0, i11 = cy1 * T + cx1;
      {
        const float* img = uvmap;
        float v00 = img[i00] * m00, v01 = img[i01] * m01;
        float v10 = img[i10] * m10, v11 = img[i11] * m11;
        o0 = ((v00 * w00 + v01 * w01) + v10 * w10) + v11 * w11;
      }
      {
        const float* img = uvmap + TT;
        float v00 = img[i00] * m00, v01 = img[i01] * m01;
        float v10 = img[i10] * m10, v11 = img[i11] * m11;
        o1 = ((v00 * w00 + v01 * w01) + v10 * w10) + v11 * w11;
      }
      {
        const float* img = uvmap + 2 * TT;
        float v00 = img[i00] * m00, v01 = img[i01] * m01;
        float v10 = img[i10] * m10, v11 = img[i11] * m11;
        o2 = ((v00 * w00 + v01 * w01) + v10 * w10) + v11 * w11;
      }
      o3 = 1.0f;
    }
    int p = i * S + j;  // pix == tid: (i,j) are this pixel's coords
    int SS = S * S;
    out[p] = o0;
    out[SS + p] = o1;
    out[2 * SS + p] = o2;
    out[3 * SS + p] = o3;
  }
}

extern "C" void kernel_launch(void* const* d_in, const int* in_sizes, int n_in,
                              void* d_out, int out_size, void* d_ws,
                              size_t ws_size, hipStream_t stream) {
  const float* verts = (const float*)d_in[0];
  const int* faces = (const int*)d_in[1];
  const float* uv = (const float*)d_in[2];
  const int* uvfaces = (const int*)d_in[3];
  const float* uvmap = (const float*)d_in[4];
  int V = in_sizes[0] / 3;
  int K = in_sizes[1] / 3;
  int T = (int)lroundf(sqrtf((float)(in_sizes[4] / 3)));
  int S = (int)lroundf(sqrtf((float)(out_size / 4)));
  float* outp = (float*)d_out;

  char* ws = (char*)d_ws;
  size_t off = 0;
  auto alloc = [&](size_t bytes) {
    void* p = ws + off;
    off = (off + bytes + 255) & ~(size_t)255;
    return p;
  };
  float* zinit = (float*)alloc(4);
  int* counter = (int*)alloc(4);
  TriRec* rec = (TriRec*)alloc((size_t)MAXK * sizeof(TriRec));  // 128-aligned
  float4* bboxS = (float4*)alloc((size_t)MAXK * 16);
  float4* planeS = (float4*)alloc((size_t)MAXK * 16);
  int* slotOf = (int*)alloc((size_t)K * 4);
  TriUV* tuv = (TriUV*)alloc((size_t)K * sizeof(TriUV));

  hipMemsetAsync(counter, 0, 4, stream);  // reset before prep's atomicAdds
  int pblocks = 1 + (K + 255) / 256;
  prep_kernel<<<pblocks, 256, 0, stream>>>(verts, faces, uv, uvfaces, V, K,
                                           rec, bboxS, planeS, slotOf, tuv,
                                           zinit, counter);
  int tiles = (S >> 4) * (S >> 4);
  render_kernel<<<tiles, 1024, 0, stream>>>(rec, bboxS, planeS, counter,
                                            slotOf, tuv, zinit, uvmap, T,
                                            outp, S);
}

// Round 10
// 33.681 us; speedup vs baseline: 1.0167x; 1.0167x over previous
//
#include <hip/hip_runtime.h>
#include <hip/hip_fp16.h>
#include <cmath>

// Match XLA/numpy: no FMA contraction anywhere (a*b - c*d must be two ops).
#pragma clang fp contract(off)

#define MAXK 2048  // next pow2 >= K (K=2000)

struct TriUV {
  float u0x, u0y, u1x, u1y;
  float u2x, u2y, pad0, pad1;
};

// All per-visit tri data in ONE 128B cache line (128-aligned).
struct __align__(128) TriRec {
  uint4 ap;     // fp16 edge coeffs packed
  float4 mt;    // M, fC, orig-as-float, 0
  float4 q0;    // t1x,t1y,dAy,dAx
  float4 q1;    // t2x,t2y,dBy,dBx
  float4 q2;    // t0x,t0y,dCy,dCx
  float4 q3;    // z0,z1,z2,w
  float4 pad0, pad1;  // -> 128B
};

__device__ __forceinline__ float h2f(unsigned v) {
  __half_raw r; r.x = (unsigned short)v;
  return __half2float(__half(r));
}
__device__ __forceinline__ unsigned f2h(float v) {
  return (unsigned)__half_as_ushort(__float2half(v));
}
__device__ __forceinline__ unsigned pkh(float lo, float hi) {
  return f2h(lo) | (f2h(hi) << 16);
}
// order-preserving float<->uint map (monotone for all finite floats)
__device__ __forceinline__ unsigned fmapu(float f) {
  unsigned b = __float_as_uint(f);
  return (b & 0x80000000u) ? ~b : (b | 0x80000000u);
}
__device__ __forceinline__ float funmap(unsigned m) {
  return __uint_as_float((m & 0x80000000u) ? (m ^ 0x80000000u) : ~m);
}

// jnp.linspace(-1, 1, n): start*(1-step) + stop*step with step=i/(n-1),
// endpoint concatenated exactly.
__device__ __forceinline__ float lin_at(int i, int n) {
#pragma clang fp contract(off)
  if (i == n - 1) return 1.0f;
  float step = (float)i / (float)(n - 1);
  return (-1.0f) * (1.0f - step) + 1.0f * step;
}

// PARALLEL single-pass prep: no global ordering needed (render re-sorts
// per-tile by its own gate; winner = order-independent lex-max of (z,orig)).
// slot == t identity. Invalid tris write a never-passing bbox only.
// Block 0: minz reduction. Blocks 1..: 256 tris each.
__global__ __launch_bounds__(256) void prep_kernel(
    const float* __restrict__ verts, const int* __restrict__ faces,
    const float* __restrict__ uv, const int* __restrict__ uvfaces, int V, int K,
    TriRec* __restrict__ rec, float4* __restrict__ bboxS,
    float4* __restrict__ planeS, TriUV* __restrict__ tuv,
    float* __restrict__ zinit) {
#pragma clang fp contract(off)
  __shared__ float smz[256];
  int tid = (int)threadIdx.x;
  int bid = (int)blockIdx.x;
  if (bid == 0) {
    float m = 3.402823466e38f;
    for (int i = tid; i < V; i += 256) m = fminf(m, verts[3 * i + 2]);
    smz[tid] = m;
    __syncthreads();
    for (int s2 = 128; s2 > 0; s2 >>= 1) {
      if (tid < s2) smz[tid] = fminf(smz[tid], smz[tid + s2]);
      __syncthreads();
    }
    if (tid == 0) *zinit = smz[0];
    return;
  }
  int t = (bid - 1) * 256 + tid;
  if (t >= K) return;
  int i0 = faces[3 * t + 0], i1 = faces[3 * t + 1], i2 = faces[3 * t + 2];
  float t0x = verts[3 * i0 + 0], t0y = verts[3 * i0 + 1], z0 = verts[3 * i0 + 2];
  float t1x = verts[3 * i1 + 0], t1y = verts[3 * i1 + 1], z1 = verts[3 * i1 + 2];
  float t2x = verts[3 * i2 + 0], t2y = verts[3 * i2 + 1], z2 = verts[3 * i2 + 2];
  int j0 = uvfaces[3 * t + 0], j1 = uvfaces[3 * t + 1], j2 = uvfaces[3 * t + 2];
  TriUV u;
  u.u0x = uv[2 * j0 + 0] * 2.0f - 1.0f;
  u.u0y = uv[2 * j0 + 1] * 2.0f - 1.0f;
  u.u1x = uv[2 * j1 + 0] * 2.0f - 1.0f;
  u.u1y = uv[2 * j1 + 1] * 2.0f - 1.0f;
  u.u2x = uv[2 * j2 + 0] * 2.0f - 1.0f;
  u.u2y = uv[2 * j2 + 1] * 2.0f - 1.0f;
  u.pad0 = 0.0f; u.pad1 = 0.0f;
  tuv[t] = u;
  // w == normal_z bitwise: valid & (w>=EPS) <=> w >= 1e-9f
  float w = (t1x - t0x) * (t2y - t0y) - (t1y - t0y) * (t2x - t0x);
  if (w < 1e-9f) {
    // never passes the tile bbox test; no other array is read for this t
    bboxS[t] = make_float4(3.0e38f, -3.0e38f, 3.0e38f, -3.0e38f);
    return;
  }
  float dAy = t0y - t1y, dAx = t0x - t1x;  // edge A (pAB), anchor t1
  float dBy = t1y - t2y, dBx = t1x - t2x;  // edge B (pCB), anchor t2
  float dCy = t2y - t0y, dCx = t2x - t0x;  // edge C (pCA), anchor t0
  bboxS[t] = make_float4(fminf(fminf(t0x, t1x), t2x),
                         fmaxf(fmaxf(t0x, t1x), t2x),
                         fminf(fminf(t0y, t1y), t2y),
                         fmaxf(fmaxf(t0y, t1y), t2y));
  // Approx edge form: p ~= px*d - py*e + f, f = b*e - a*d (anchor (a,b)).
  float fA = t1y * dAx - t1x * dAy;
  float fB = t2y * dBx - t2x * dBy;
  float fC = t0y * dCx - t0x * dCy;
  // Sound margin: fp16 quantization + fp32 fma + exact-expr rounding.
  float sA = fabsf(dAy) + fabsf(dAx) + fabsf(fA);
  float sB = fabsf(dBy) + fabsf(dBx) + fabsf(fB);
  float sC = fabsf(dCy) + fabsf(dCx) + fabsf(fC);
  float M = fmaxf(fmaxf(sA, sB), sC) * 9.766e-4f + 1e-4f;
  TriRec r;
  r.ap = make_uint4(pkh(dAy, dAx), pkh(fA, dBy), pkh(dBx, fB), pkh(dCy, dCx));
  r.mt = make_float4(M, fC, __int_as_float(t), 0.0f);
  r.q0 = make_float4(t1x, t1y, dAy, dAx);
  r.q1 = make_float4(t2x, t2y, dBy, dBx);
  r.q2 = make_float4(t0x, t0y, dCy, dCx);
  r.q3 = make_float4(z0, z1, z2, w);
  r.pad0 = make_float4(0.f, 0.f, 0.f, 0.f);
  r.pad1 = make_float4(0.f, 0.f, 0.f, 0.f);
  rec[t] = r;
  // z plane: z(x,y) = (z0*pCB + z1*pCA + z2*pAB)/w is affine in (x,y).
  // pXX(0,0) = fB/fC/fA; d(pCB)/dx = dBy, d(pCA)/dx = dCy, d(pAB)/dx = dAy.
  float zmx = fmaxf(fmaxf(z0, z1), z2);
  float gatef = zmx + 1e-3f + 1e-4f / w;  // exact global gate (strict UB)
  float gx = (z0 * dBy + z1 * dCy + z2 * dAy) / w;
  float gy = -(z0 * dBx + z1 * dCx + z2 * dAx) / w;
  float cc = (z0 * fB + z1 * fC + z2 * fA) / w;
  // margin: coefficient fp error (magnitude-scaled) + render-side eval
  // rounding + established inner-z error (1e-3 + 1e-4/w) + abs cushion.
  float mm = (fabsf(z0 * fB) + fabsf(z1 * fC) + fabsf(z2 * fA) +
              fabsf(z0 * dBy) + fabsf(z1 * dCy) + fabsf(z2 * dAy) +
              fabsf(z0 * dBx) + fabsf(z1 * dCx) + fabsf(z2 * dAx)) *
                 (2e-6f / w) +
             1e-3f + 1e-4f / w + 1e-4f;
  planeS[t] = make_float4(gx, gy, cc + mm, gatef);
}

// 16x16 tile, 1024 threads = 16 waves (R6 structure — best measured).
// Wave wv: substream s=wv>>2 (parity-4 of the per-tile-gate-sorted list),
// quadrant q=wv&3 (lane ln -> pixel q*64+ln). Per-pixel winner = 64-bit LDS
// atomicMax of (map(z)<<32 | orig+1): exact lex-max of (z, orig).
// Phase 0 sorts bbox-survivors by tg = min(globalGate, planeZmaxOverTile+m).
// Phase 1: GROUP-OF-4 scalar scan — 4 independent ds_read_b128 (latency
// overlapped), ONE zb read + ONE break ballot per group. Group-start zb in
// the pretest is staler = strictly conservative (superset of R6's visits);
// deep path (fresh pregate, IEEE div, atomicMax) is bitwise identical.
// Sentinel entries (em=tg=0: always skipped, em<zb) pad the tail so no
// per-entry bounds checks are needed; break on the group's FIRST entry is
// exactly R6's monotone-edge break.
__global__ __launch_bounds__(1024) void render_kernel(
    const TriRec* __restrict__ rec, const float4* __restrict__ bboxS,
    const float4* __restrict__ planeS, int N, const TriUV* __restrict__ tuv,
    const float* __restrict__ zinitp, const float* __restrict__ uvmap, int T,
    float* __restrict__ out, int S) {
#pragma clang fp contract(off)
  __shared__ uint4 s_g[MAXK + 16];              // 32KB+256B (em, tg, idx, 0)
  __shared__ unsigned long long s_key[256];     // 2KB winner (z,orig+1)
  __shared__ unsigned s_zu[256];                // 1KB pruning max (mapped z)
  __shared__ unsigned s_hist[256];              // 1KB
  __shared__ int s_cur[256];                    // 1KB
  __shared__ unsigned s_wsum[4];                // -> ~37KB total

  int tid = (int)threadIdx.x;
  int wv = tid >> 6, ln = tid & 63;
  int s = wv >> 2, q = wv & 3;
  int pix = (q << 6) + ln;
  int tilesX = S >> 4;
  int tileX = (int)blockIdx.x % tilesX;
  int tileY = (int)blockIdx.x / tilesX;
  int j = (tileX << 4) + (pix & 15);
  int i = (tileY << 4) + (pix >> 4);
  // pts[i][j] = (lin[j], lin[S-1-i])  (rot90 of meshgrid)
  float px = lin_at(j, S);
  float py = lin_at(S - 1 - i, S);
  float pxlo = lin_at(tileX << 4, S);
  float pxhi = lin_at((tileX << 4) + 15, S);
  float pylo = lin_at(S - 1 - ((tileY << 4) + 15), S);
  float pyhi = lin_at(S - 1 - (tileY << 4), S);

  float zinit = *zinitp;
  unsigned zinit_m = fmapu(zinit);
  if (tid < 256) {
    s_zu[tid] = zinit_m;
    s_key[tid] = ((unsigned long long)zinit_m << 32);  // orig+1 = 0 -> none
    s_hist[tid] = 0u;
  }
  volatile unsigned* vzu = s_zu;
  __syncthreads();

  // ---- Phase 0: bbox cull + per-tile gate + 256-bucket counting sort ----
  bool kA = false, kB = false;
  int bA = 0, bB = 0;
  unsigned gA = 0, gB = 0;
  {
    int t = tid;
    if (t < N) {
      float4 bb = bboxS[t];  // xmin,xmax,ymin,ymax
      if (bb.x <= pxhi && bb.y >= pxlo && bb.z <= pyhi && bb.w >= pylo) {
        float4 pl = planeS[t];  // gx, gy, c+margin, globalGate
        float ub = pl.z + fmaxf(pl.x * pxlo, pl.x * pxhi) +
                   fmaxf(pl.y * pylo, pl.y * pyhi);
        float tg = fminf(pl.w, ub);
        kA = true;
        bA = min(max((int)((4.0f - tg) * 32.0f), 0), 255);
        gA = fmapu(tg);
      }
    }
    t = tid + 1024;
    if (t < N) {
      float4 bb = bboxS[t];
      if (bb.x <= pxhi && bb.y >= pxlo && bb.z <= pyhi && bb.w >= pylo) {
        float4 pl = planeS[t];
        float ub = pl.z + fmaxf(pl.x * pxlo, pl.x * pxhi) +
                   fmaxf(pl.y * pylo, pl.y * pyhi);
        float tg = fminf(pl.w, ub);
        kB = true;
        bB = min(max((int)((4.0f - tg) * 32.0f), 0), 255);
        gB = fmapu(tg);
      }
    }
  }
  if (kA) atomicAdd(&s_hist[bA], 1u);
  if (kB) atomicAdd(&s_hist[bB], 1u);
  __syncthreads();
  // 256-bin inclusive scan: 4 waves shuffle-scan 64 bins each + fixup.
  unsigned hx = 0, hinc = 0;
  if (tid < 256) {
    hx = s_hist[tid];
    unsigned v = hx;
#pragma unroll
    for (int d = 1; d < 64; d <<= 1) {
      unsigned tv = __shfl_up(v, d, 64);
      if (ln >= d) v += tv;
    }
    if (ln == 63) s_wsum[wv] = v;
    hinc = v;
  }
  __syncthreads();
  if (tid < 256) {
    unsigned add = 0;
    for (int w2 = 0; w2 < wv; ++w2) add += s_wsum[w2];
    hinc += add;
    s_hist[tid] = hinc;                 // inclusive totals (nk at bin 255)
    s_cur[tid] = (int)(hinc - hx);      // exclusive start cursor
  }
  __syncthreads();
  int nk = (int)s_hist[255];
  if (tid < 16) s_g[nk + tid] = make_uint4(0u, 0u, 0u, 0u);  // sentinels
  if (kA) {
    int sl = atomicAdd(&s_cur[bA], 1);
    float ef = (bA == 0) ? 3.402823466e38f : (4.0f - (float)bA * 0.03125f);
    s_g[sl] = make_uint4(fmapu(ef), gA, (unsigned)tid, 0u);
  }
  if (kB) {
    int sl = atomicAdd(&s_cur[bB], 1);
    float ef = (bB == 0) ? 3.402823466e38f : (4.0f - (float)bB * 0.03125f);
    s_g[sl] = make_uint4(fmapu(ef), gB, (unsigned)(tid + 1024), 0u);
  }
  __syncthreads();

  // ---- Phase 1: group-of-4 parity-4 scan, continuous shared-z pruning ----
  {
    auto visit = [&](uint4 g, unsigned zb) {
      if (g.y >= zb) {  // provable-skip pretest (tg>=zb implies em>=zb)
        const TriRec* r = &rec[g.z];  // whole visit = one 128B line
        uint4 ap = r->ap;
        float4 mt = r->mt;
        float M = mt.x, fC = mt.y;
        // approx edges (fp16 coeffs, fp32 fma); |approx-exact| <= M
        float aA = fmaf(px, h2f(ap.x & 0xffffu),
                        fmaf(-py, h2f(ap.x >> 16), h2f(ap.y & 0xffffu)));
        float aB = fmaf(px, h2f(ap.y >> 16),
                        fmaf(-py, h2f(ap.z & 0xffffu), h2f(ap.z >> 16)));
        float aC = fmaf(px, h2f(ap.w & 0xffffu),
                        fmaf(-py, h2f(ap.w >> 16), fC));
        if (fminf(fminf(aA, aB), aC) > -M) {  // not provably outside
          float4 q0 = r->q0, q1 = r->q1, q2 = r->q2;
          float pAB = (px - q0.x) * q0.z - (py - q0.y) * q0.w;
          float pCB = (px - q1.x) * q1.z - (py - q1.y) * q1.w;
          float pCA = (px - q2.x) * q2.z - (py - q2.y) * q2.w;
          if (pAB > 0.0f && pCB > 0.0f && pCA > 0.0f) {
            float4 q3 = r->q3;
            float w = q3.w;
            float bzf = funmap(vzu[pix]);  // fresh on deep path
            // scaled z pregate: skip divides when provably losing
            float zs = (pCB * q3.x + pCA * q3.y) + ((w - pCB) - pCA) * q3.z;
            if (w < 1e-3f || zs >= (bzf - 1e-3f) * w) {
              float w1 = pCB / w;  // IEEE div, bitwise == reference
              float w2 = pCA / w;
              float w3 = (1.0f - w1) - w2;
              float z = (w1 * q3.x + w2 * q3.y) + w3 * q3.z;
              int o = __float_as_int(mt.z);
              unsigned zm = fmapu(z);
              unsigned long long key =
                  ((unsigned long long)zm << 32) | (unsigned)(o + 1);
              atomicMax(&s_key[pix], key);
              atomicMax(&s_zu[pix], zm);
            }
          }
        }
      }
    };
    for (int a = s; a < nk; a += 16) {
      uint4 g0 = s_g[a], g1 = s_g[a + 4], g2 = s_g[a + 8], g3 = s_g[a + 12];
      unsigned zb = vzu[pix];  // one refresh per group
      // em monotone along substream: first entry dead for all lanes ->
      // every remaining entry provably loses -> stop (== R6's break).
      if (__all(g0.x < zb)) break;
      visit(g0, zb);
      visit(g1, zb);
      visit(g2, zb);
      visit(g3, zb);
    }
  }
  __syncthreads();

  // ---- Epilogue (tid<256, pix==tid): unpack winner, recompute w1/w2 ----
  if (tid < 256) {
    unsigned long long key = s_key[tid];
    unsigned oP1 = (unsigned)(key & 0xFFFFFFFFULL);
    float o0 = 0.0f, o1 = 0.0f, o2 = 0.0f, o3 = 0.0f;
    if (oP1 != 0) {
      int o = (int)oP1 - 1;  // slot == orig (identity)
      const TriRec* r = &rec[o];
      float4 q1 = r->q1, q2 = r->q2, q3 = r->q3;
      float pCB = (px - q1.x) * q1.z - (py - q1.y) * q1.w;
      float pCA = (px - q2.x) * q2.z - (py - q2.y) * q2.w;
      float w1 = pCB / q3.w;  // bitwise == inner-loop values
      float w2 = pCA / q3.w;
      float w3 = (1.0f - w1) - w2;
      TriUV u = tuv[o];
      float x = (w1 * u.u0x + w2 * u.u1x) + w3 * u.u2x;
      float y = (w1 * u.u0y + w2 * u.u1y) + w3 * u.u2y;
      float WH = (float)(T - 1);
      float fx = ((x + 1.0f) * WH) * 0.5f;
      float fy = ((y + 1.0f) * WH) * 0.5f;
      float ix0 = floorf(fx), iy0 = floorf(fy);
      float ix1 = ix0 + 1.0f, iy1 = iy0 + 1.0f;
      float wx1 = fx - ix0, wx0 = 1.0f - wx1;
      float wy1 = fy - iy0, wy0 = 1.0f - wy1;
      float w00 = wy0 * wx0, w01 = wy0 * wx1;
      float w10 = wy1 * wx0, w11 = wy1 * wx1;
      bool bx0 = (ix0 >= 0.0f) && (ix0 <= WH);
      bool bx1 = (ix1 >= 0.0f) && (ix1 <= WH);
      bool by0 = (iy0 >= 0.0f) && (iy0 <= WH);
      bool by1 = (iy1 >= 0.0f) && (iy1 <= WH);
      float m00 = (by0 && bx0) ? 1.0f : 0.0f;
      float m01 = (by0 && bx1) ? 1.0f : 0.0f;
      float m10 = (by1 && bx0) ? 1.0f : 0.0f;
      float m11 = (by1 && bx1) ? 1.0f : 0.0f;
      int cx0 = (int)fminf(fmaxf(ix0, 0.0f), WH);
      int cx1 = (int)fminf(fmaxf(ix1, 0.0f), WH);
      int cy0 = (int)fminf(fmaxf(iy0, 0.0f), WH);
      int cy1 = (int)fminf(fmaxf(iy1, 0.0f), WH);
      int TT = T * T;
      int i00 = cy0 * T + cx0, i01 = cy0 * T + cx1;
      int i10 = cy1 * T + cx0, i11 = cy1 * T + cx1;
      {
        const float* img = uvmap;
        float v00 = img[i00] * m00, v01 = img[i01] * m01;
        float v10 = img[i10] * m10, v11 = img[i11] * m11;
        o0 = ((v00 * w00 + v01 * w01) + v10 * w10) + v11 * w11;
      }
      {
        const float* img = uvmap + TT;
        float v00 = img[i00] * m00, v01 = img[i01] * m01;
        float v10 = img[i10] * m10, v11 = img[i11] * m11;
        o1 = ((v00 * w00 + v01 * w01) + v10 * w10) + v11 * w11;
      }
      {
        const float* img = uvmap + 2 * TT;
        float v00 = img[i00] * m00, v01 = img[i01] * m01;
        float v10 = img[i10] * m10, v11 = img[i11] * m11;
        o2 = ((v00 * w00 + v01 * w01) + v10 * w10) + v11 * w11;
      }
      o3 = 1.0f;
    }
    int p = i * S + j;  // pix == tid: (i,j) are this pixel's coords
    int SS = S * S;
    out[p] = o0;
    out[SS + p] = o1;
    out[2 * SS + p] = o2;
    out[3 * SS + p] = o3;
  }
}

extern "C" void kernel_launch(void* const* d_in, const int* in_sizes, int n_in,
                              void* d_out, int out_size, void* d_ws,
                              size_t ws_size, hipStream_t stream) {
  const float* verts = (const float*)d_in[0];
  const int* faces = (const int*)d_in[1];
  const float* uv = (const float*)d_in[2];
  const int* uvfaces = (const int*)d_in[3];
  const float* uvmap = (const float*)d_in[4];
  int V = in_sizes[0] / 3;
  int K = in_sizes[1] / 3;
  int T = (int)lroundf(sqrtf((float)(in_sizes[4] / 3)));
  int S = (int)lroundf(sqrtf((float)(out_size / 4)));
  float* outp = (float*)d_out;

  char* ws = (char*)d_ws;
  size_t off = 0;
  auto alloc = [&](size_t bytes) {
    void* p = ws + off;
    off = (off + bytes + 255) & ~(size_t)255;
    return p;
  };
  float* zinit = (float*)alloc(4);
  TriRec* rec = (TriRec*)alloc((size_t)MAXK * sizeof(TriRec));  // 128-aligned
  float4* bboxS = (float4*)alloc((size_t)MAXK * 16);
  float4* planeS = (float4*)alloc((size_t)MAXK * 16);
  TriUV* tuv = (TriUV*)alloc((size_t)K * sizeof(TriUV));

  int pblocks = 1 + (K + 255) / 256;
  prep_kernel<<<pblocks, 256, 0, stream>>>(verts, faces, uv, uvfaces, V, K,
                                           rec, bboxS, planeS, tuv, zinit);
  int tiles = (S >> 4) * (S >> 4);
  render_kernel<<<tiles, 1024, 0, stream>>>(rec, bboxS, planeS, K, tuv, zinit,
                                            uvmap, T, outp, S);
}

// Round 11
// 28.463 us; speedup vs baseline: 1.2031x; 1.1833x over previous
//
#include <hip/hip_runtime.h>
#include <hip/hip_fp16.h>
#include <cmath>

// Match XLA/numpy: no FMA contraction anywhere (a*b - c*d must be two ops).
#pragma clang fp contract(off)

#define MAXK 2048  // next pow2 >= K (K=2000)

struct TriUV {
  float u0x, u0y, u1x, u1y;
  float u2x, u2y, pad0, pad1;
};

// All per-visit tri data in ONE 128B cache line (128-aligned).
struct __align__(128) TriRec {
  uint4 ap;     // fp16 edge coeffs packed
  float4 mt;    // M, fC, orig-as-float, 0
  float4 q0;    // t1x,t1y,dAy,dAx
  float4 q1;    // t2x,t2y,dBy,dBx
  float4 q2;    // t0x,t0y,dCy,dCx
  float4 q3;    // z0,z1,z2,w
  float4 pad0, pad1;  // -> 128B
};

__device__ __forceinline__ float h2f(unsigned v) {
  __half_raw r; r.x = (unsigned short)v;
  return __half2float(__half(r));
}
__device__ __forceinline__ unsigned f2h(float v) {
  return (unsigned)__half_as_ushort(__float2half(v));
}
__device__ __forceinline__ unsigned pkh(float lo, float hi) {
  return f2h(lo) | (f2h(hi) << 16);
}
// order-preserving float<->uint map (monotone for all finite floats)
__device__ __forceinline__ unsigned fmapu(float f) {
  unsigned b = __float_as_uint(f);
  return (b & 0x80000000u) ? ~b : (b | 0x80000000u);
}
__device__ __forceinline__ float funmap(unsigned m) {
  return __uint_as_float((m & 0x80000000u) ? (m ^ 0x80000000u) : ~m);
}

// jnp.linspace(-1, 1, n): start*(1-step) + stop*step with step=i/(n-1),
// endpoint concatenated exactly.
__device__ __forceinline__ float lin_at(int i, int n) {
#pragma clang fp contract(off)
  if (i == n - 1) return 1.0f;
  float step = (float)i / (float)(n - 1);
  return (-1.0f) * (1.0f - step) + 1.0f * step;
}

// PARALLEL single-pass prep: no global ordering needed (render re-sorts
// per-tile by its own gate; winner = order-independent lex-max of (z,orig)).
// slot == t identity. Invalid tris write a never-passing bbox only.
// Block 0: minz reduction. Blocks 1..: 256 tris each.
__global__ __launch_bounds__(256) void prep_kernel(
    const float* __restrict__ verts, const int* __restrict__ faces,
    const float* __restrict__ uv, const int* __restrict__ uvfaces, int V, int K,
    TriRec* __restrict__ rec, float4* __restrict__ bboxS,
    float4* __restrict__ planeS, TriUV* __restrict__ tuv,
    float* __restrict__ zinit) {
#pragma clang fp contract(off)
  __shared__ float smz[256];
  int tid = (int)threadIdx.x;
  int bid = (int)blockIdx.x;
  if (bid == 0) {
    float m = 3.402823466e38f;
    for (int i = tid; i < V; i += 256) m = fminf(m, verts[3 * i + 2]);
    smz[tid] = m;
    __syncthreads();
    for (int s2 = 128; s2 > 0; s2 >>= 1) {
      if (tid < s2) smz[tid] = fminf(smz[tid], smz[tid + s2]);
      __syncthreads();
    }
    if (tid == 0) *zinit = smz[0];
    return;
  }
  int t = (bid - 1) * 256 + tid;
  if (t >= K) return;
  int i0 = faces[3 * t + 0], i1 = faces[3 * t + 1], i2 = faces[3 * t + 2];
  float t0x = verts[3 * i0 + 0], t0y = verts[3 * i0 + 1], z0 = verts[3 * i0 + 2];
  float t1x = verts[3 * i1 + 0], t1y = verts[3 * i1 + 1], z1 = verts[3 * i1 + 2];
  float t2x = verts[3 * i2 + 0], t2y = verts[3 * i2 + 1], z2 = verts[3 * i2 + 2];
  int j0 = uvfaces[3 * t + 0], j1 = uvfaces[3 * t + 1], j2 = uvfaces[3 * t + 2];
  TriUV u;
  u.u0x = uv[2 * j0 + 0] * 2.0f - 1.0f;
  u.u0y = uv[2 * j0 + 1] * 2.0f - 1.0f;
  u.u1x = uv[2 * j1 + 0] * 2.0f - 1.0f;
  u.u1y = uv[2 * j1 + 1] * 2.0f - 1.0f;
  u.u2x = uv[2 * j2 + 0] * 2.0f - 1.0f;
  u.u2y = uv[2 * j2 + 1] * 2.0f - 1.0f;
  u.pad0 = 0.0f; u.pad1 = 0.0f;
  tuv[t] = u;
  // w == normal_z bitwise: valid & (w>=EPS) <=> w >= 1e-9f
  float w = (t1x - t0x) * (t2y - t0y) - (t1y - t0y) * (t2x - t0x);
  if (w < 1e-9f) {
    // never passes the tile bbox test; no other array is read for this t
    bboxS[t] = make_float4(3.0e38f, -3.0e38f, 3.0e38f, -3.0e38f);
    return;
  }
  float dAy = t0y - t1y, dAx = t0x - t1x;  // edge A (pAB), anchor t1
  float dBy = t1y - t2y, dBx = t1x - t2x;  // edge B (pCB), anchor t2
  float dCy = t2y - t0y, dCx = t2x - t0x;  // edge C (pCA), anchor t0
  bboxS[t] = make_float4(fminf(fminf(t0x, t1x), t2x),
                         fmaxf(fmaxf(t0x, t1x), t2x),
                         fminf(fminf(t0y, t1y), t2y),
                         fmaxf(fmaxf(t0y, t1y), t2y));
  // Approx edge form: p ~= px*d - py*e + f, f = b*e - a*d (anchor (a,b)).
  float fA = t1y * dAx - t1x * dAy;
  float fB = t2y * dBx - t2x * dBy;
  float fC = t0y * dCx - t0x * dCy;
  // Sound margin: fp16 quantization + fp32 fma + exact-expr rounding.
  float sA = fabsf(dAy) + fabsf(dAx) + fabsf(fA);
  float sB = fabsf(dBy) + fabsf(dBx) + fabsf(fB);
  float sC = fabsf(dCy) + fabsf(dCx) + fabsf(fC);
  float M = fmaxf(fmaxf(sA, sB), sC) * 9.766e-4f + 1e-4f;
  TriRec r;
  r.ap = make_uint4(pkh(dAy, dAx), pkh(fA, dBy), pkh(dBx, fB), pkh(dCy, dCx));
  r.mt = make_float4(M, fC, __int_as_float(t), 0.0f);
  r.q0 = make_float4(t1x, t1y, dAy, dAx);
  r.q1 = make_float4(t2x, t2y, dBy, dBx);
  r.q2 = make_float4(t0x, t0y, dCy, dCx);
  r.q3 = make_float4(z0, z1, z2, w);
  r.pad0 = make_float4(0.f, 0.f, 0.f, 0.f);
  r.pad1 = make_float4(0.f, 0.f, 0.f, 0.f);
  rec[t] = r;
  // z plane: z(x,y) = (z0*pCB + z1*pCA + z2*pAB)/w is affine in (x,y).
  // pXX(0,0) = fB/fC/fA; d(pCB)/dx = dBy, d(pCA)/dx = dCy, d(pAB)/dx = dAy.
  float zmx = fmaxf(fmaxf(z0, z1), z2);
  float gatef = zmx + 1e-3f + 1e-4f / w;  // exact global gate (strict UB)
  float gx = (z0 * dBy + z1 * dCy + z2 * dAy) / w;
  float gy = -(z0 * dBx + z1 * dCx + z2 * dAx) / w;
  float cc = (z0 * fB + z1 * fC + z2 * fA) / w;
  // margin: coefficient fp error (magnitude-scaled) + render-side eval
  // rounding + established inner-z error (1e-3 + 1e-4/w) + abs cushion.
  float mm = (fabsf(z0 * fB) + fabsf(z1 * fC) + fabsf(z2 * fA) +
              fabsf(z0 * dBy) + fabsf(z1 * dCy) + fabsf(z2 * dAy) +
              fabsf(z0 * dBx) + fabsf(z1 * dCx) + fabsf(z2 * dAx)) *
                 (2e-6f / w) +
             1e-3f + 1e-4f / w + 1e-4f;
  planeS[t] = make_float4(gx, gy, cc + mm, gatef);
}

// 16x16 tile, 512 threads = 8 waves, 4 BLOCKS/CU (single-round residency:
// all 1024 tiles co-resident -> no round-boundary straggler tail).
// Wave wv: substream s=wv>>2 in {0,1} (parity-2 of the per-tile-gate-sorted
// list), quadrant q=wv&3 (lane ln -> pixel q*64+ln; 2 waves per pixel).
// Per-pixel winner = 64-bit LDS atomicMax of (map(z)<<32 | orig+1): exact
// lex-max of (z, orig). Phase 0 sorts bbox-survivors by
// tg = min(globalGate, planeZmaxOverTile + margin).
// Phase 1 body is byte-for-byte R6's scalar loop (best measured), stride 2.
__global__ __launch_bounds__(512) void render_kernel(
    const TriRec* __restrict__ rec, const float4* __restrict__ bboxS,
    const float4* __restrict__ planeS, int N, const TriUV* __restrict__ tuv,
    const float* __restrict__ zinitp, const float* __restrict__ uvmap, int T,
    float* __restrict__ out, int S) {
#pragma clang fp contract(off)
  __shared__ uint4 s_g[MAXK];                   // 32KB (em, tg, idx, 0)
  __shared__ unsigned long long s_key[256];     // 2KB winner (z,orig+1)
  __shared__ unsigned s_zu[256];                // 1KB pruning max (mapped z)
  __shared__ unsigned s_hist[256];              // 1KB
  __shared__ int s_cur[256];                    // 1KB
  __shared__ unsigned s_wsum[4];                // -> ~37KB total (4/CU fits)

  int tid = (int)threadIdx.x;
  int wv = tid >> 6, ln = tid & 63;
  int s = wv >> 2, q = wv & 3;   // s in {0,1}, q in {0..3}
  int pix = (q << 6) + ln;
  int tilesX = S >> 4;
  int tileX = (int)blockIdx.x % tilesX;
  int tileY = (int)blockIdx.x / tilesX;
  int j = (tileX << 4) + (pix & 15);
  int i = (tileY << 4) + (pix >> 4);
  // pts[i][j] = (lin[j], lin[S-1-i])  (rot90 of meshgrid)
  float px = lin_at(j, S);
  float py = lin_at(S - 1 - i, S);
  float pxlo = lin_at(tileX << 4, S);
  float pxhi = lin_at((tileX << 4) + 15, S);
  float pylo = lin_at(S - 1 - ((tileY << 4) + 15), S);
  float pyhi = lin_at(S - 1 - (tileY << 4), S);

  float zinit = *zinitp;
  unsigned zinit_m = fmapu(zinit);
  if (tid < 256) {
    s_zu[tid] = zinit_m;
    s_key[tid] = ((unsigned long long)zinit_m << 32);  // orig+1 = 0 -> none
    s_hist[tid] = 0u;
  }
  volatile unsigned* vzu = s_zu;
  __syncthreads();

  // ---- Phase 0: bbox cull + per-tile gate + 256-bucket counting sort ----
  bool kk[4] = {false, false, false, false};
  int bb4[4] = {0, 0, 0, 0};
  unsigned gg[4] = {0, 0, 0, 0};
#pragma unroll
  for (int c = 0; c < 4; ++c) {
    int t = tid + (c << 9);  // tid + c*512
    if (t < N) {
      float4 bb = bboxS[t];  // xmin,xmax,ymin,ymax
      if (bb.x <= pxhi && bb.y >= pxlo && bb.z <= pyhi && bb.w >= pylo) {
        float4 pl = planeS[t];  // gx, gy, c+margin, globalGate
        float ub = pl.z + fmaxf(pl.x * pxlo, pl.x * pxhi) +
                   fmaxf(pl.y * pylo, pl.y * pyhi);
        float tg = fminf(pl.w, ub);
        kk[c] = true;
        bb4[c] = min(max((int)((4.0f - tg) * 32.0f), 0), 255);
        gg[c] = fmapu(tg);
      }
    }
  }
#pragma unroll
  for (int c = 0; c < 4; ++c)
    if (kk[c]) atomicAdd(&s_hist[bb4[c]], 1u);
  __syncthreads();
  // 256-bin inclusive scan: 4 waves shuffle-scan 64 bins each + fixup.
  unsigned hx = 0, hinc = 0;
  if (tid < 256) {
    hx = s_hist[tid];
    unsigned v = hx;
#pragma unroll
    for (int d = 1; d < 64; d <<= 1) {
      unsigned tv = __shfl_up(v, d, 64);
      if (ln >= d) v += tv;
    }
    if (ln == 63) s_wsum[wv] = v;
    hinc = v;
  }
  __syncthreads();
  if (tid < 256) {
    unsigned add = 0;
    for (int w2 = 0; w2 < wv; ++w2) add += s_wsum[w2];
    hinc += add;
    s_hist[tid] = hinc;                 // inclusive totals (nk at bin 255)
    s_cur[tid] = (int)(hinc - hx);      // exclusive start cursor
  }
  __syncthreads();
  int nk = (int)s_hist[255];
#pragma unroll
  for (int c = 0; c < 4; ++c) {
    if (kk[c]) {
      int sl = atomicAdd(&s_cur[bb4[c]], 1);
      float ef =
          (bb4[c] == 0) ? 3.402823466e38f : (4.0f - (float)bb4[c] * 0.03125f);
      s_g[sl] = make_uint4(fmapu(ef), gg[c], (unsigned)(tid + (c << 9)), 0u);
    }
  }
  __syncthreads();

  // ---- Phase 1: scalar parity-2 scan (R6 body), shared-z pruning ----
  for (int a = s; a < nk; a += 2) {
    uint4 g = s_g[a];        // one ds_read_b128: em, tg, idx
    unsigned zb = vzu[pix];  // fresh shared max (volatile)
    // edges monotone along substream: all lanes provably finished -> stop
    if (__all(g.x < zb)) break;
    if (g.y >= zb) {  // provable-skip pretest (tg>=zb implies em>=zb)
      const TriRec* r = &rec[g.z];  // whole visit = one 128B line
      uint4 ap = r->ap;
      float4 mt = r->mt;
      float M = mt.x, fC = mt.y;
      // approx edges (fp16 coeffs, fp32 fma); |approx-exact| <= M
      float aA = fmaf(px, h2f(ap.x & 0xffffu),
                      fmaf(-py, h2f(ap.x >> 16), h2f(ap.y & 0xffffu)));
      float aB = fmaf(px, h2f(ap.y >> 16),
                      fmaf(-py, h2f(ap.z & 0xffffu), h2f(ap.z >> 16)));
      float aC = fmaf(px, h2f(ap.w & 0xffffu),
                      fmaf(-py, h2f(ap.w >> 16), fC));
      if (fminf(fminf(aA, aB), aC) > -M) {  // not provably outside
        float4 q0 = r->q0, q1 = r->q1, q2 = r->q2;
        float pAB = (px - q0.x) * q0.z - (py - q0.y) * q0.w;
        float pCB = (px - q1.x) * q1.z - (py - q1.y) * q1.w;
        float pCA = (px - q2.x) * q2.z - (py - q2.y) * q2.w;
        if (pAB > 0.0f && pCB > 0.0f && pCA > 0.0f) {
          float4 q3 = r->q3;
          float w = q3.w;
          float bzf = funmap(vzu[pix]);
          // scaled z pregate: skip divides when provably losing
          float zs = (pCB * q3.x + pCA * q3.y) + ((w - pCB) - pCA) * q3.z;
          if (w < 1e-3f || zs >= (bzf - 1e-3f) * w) {
            float w1 = pCB / w;  // IEEE div, bitwise == reference
            float w2 = pCA / w;
            float w3 = (1.0f - w1) - w2;
            float z = (w1 * q3.x + w2 * q3.y) + w3 * q3.z;
            int o = __float_as_int(mt.z);
            unsigned zm = fmapu(z);
            unsigned long long key =
                ((unsigned long long)zm << 32) | (unsigned)(o + 1);
            atomicMax(&s_key[pix], key);
            atomicMax(&s_zu[pix], zm);
          }
        }
      }
    }
  }
  __syncthreads();

  // ---- Epilogue (tid<256, pix==tid): unpack winner, recompute w1/w2 ----
  if (tid < 256) {
    unsigned long long key = s_key[tid];
    unsigned oP1 = (unsigned)(key & 0xFFFFFFFFULL);
    float o0 = 0.0f, o1 = 0.0f, o2 = 0.0f, o3 = 0.0f;
    if (oP1 != 0) {
      int o = (int)oP1 - 1;  // slot == orig (identity)
      const TriRec* r = &rec[o];
      float4 q1 = r->q1, q2 = r->q2, q3 = r->q3;
      float pCB = (px - q1.x) * q1.z - (py - q1.y) * q1.w;
      float pCA = (px - q2.x) * q2.z - (py - q2.y) * q2.w;
      float w1 = pCB / q3.w;  // bitwise == inner-loop values
      float w2 = pCA / q3.w;
      float w3 = (1.0f - w1) - w2;
      TriUV u = tuv[o];
      float x = (w1 * u.u0x + w2 * u.u1x) + w3 * u.u2x;
      float y = (w1 * u.u0y + w2 * u.u1y) + w3 * u.u2y;
      float WH = (float)(T - 1);
      float fx = ((x + 1.0f) * WH) * 0.5f;
      float fy = ((y + 1.0f) * WH) * 0.5f;
      float ix0 = floorf(fx), iy0 = floorf(fy);
      float ix1 = ix0 + 1.0f, iy1 = iy0 + 1.0f;
      float wx1 = fx - ix0, wx0 = 1.0f - wx1;
      float wy1 = fy - iy0, wy0 = 1.0f - wy1;
      float w00 = wy0 * wx0, w01 = wy0 * wx1;
      float w10 = wy1 * wx0, w11 = wy1 * wx1;
      bool bx0 = (ix0 >= 0.0f) && (ix0 <= WH);
      bool bx1 = (ix1 >= 0.0f) && (ix1 <= WH);
      bool by0 = (iy0 >= 0.0f) && (iy0 <= WH);
      bool by1 = (iy1 >= 0.0f) && (iy1 <= WH);
      float m00 = (by0 && bx0) ? 1.0f : 0.0f;
      float m01 = (by0 && bx1) ? 1.0f : 0.0f;
      float m10 = (by1 && bx0) ? 1.0f : 0.0f;
      float m11 = (by1 && bx1) ? 1.0f : 0.0f;
      int cx0 = (int)fminf(fmaxf(ix0, 0.0f), WH);
      int cx1 = (int)fminf(fmaxf(ix1, 0.0f), WH);
      int cy0 = (int)fminf(fmaxf(iy0, 0.0f), WH);
      int cy1 = (int)fminf(fmaxf(iy1, 0.0f), WH);
      int TT = T * T;
      int i00 = cy0 * T + cx0, i01 = cy0 * T + cx1;
      int i10 = cy1 * T + cx0, i11 = cy1 * T + cx1;
      {
        const float* img = uvmap;
        float v00 = img[i00] * m00, v01 = img[i01] * m01;
        float v10 = img[i10] * m10, v11 = img[i11] * m11;
        o0 = ((v00 * w00 + v01 * w01) + v10 * w10) + v11 * w11;
      }
      {
        const float* img = uvmap + TT;
        float v00 = img[i00] * m00, v01 = img[i01] * m01;
        float v10 = img[i10] * m10, v11 = img[i11] * m11;
        o1 = ((v00 * w00 + v01 * w01) + v10 * w10) + v11 * w11;
      }
      {
        const float* img = uvmap + 2 * TT;
        float v00 = img[i00] * m00, v01 = img[i01] * m01;
        float v10 = img[i10] * m10, v11 = img[i11] * m11;
        o2 = ((v00 * w00 + v01 * w01) + v10 * w10) + v11 * w11;
      }
      o3 = 1.0f;
    }
    int p = i * S + j;  // pix == tid: (i,j) are this pixel's coords
    int SS = S * S;
    out[p] = o0;
    out[SS + p] = o1;
    out[2 * SS + p] = o2;
    out[3 * SS + p] = o3;
  }
}

extern "C" void kernel_launch(void* const* d_in, const int* in_sizes, int n_in,
                              void* d_out, int out_size, void* d_ws,
                              size_t ws_size, hipStream_t stream) {
  const float* verts = (const float*)d_in[0];
  const int* faces = (const int*)d_in[1];
  const float* uv = (const float*)d_in[2];
  const int* uvfaces = (const int*)d_in[3];
  const float* uvmap = (const float*)d_in[4];
  int V = in_sizes[0] / 3;
  int K = in_sizes[1] / 3;
  int T = (int)lroundf(sqrtf((float)(in_sizes[4] / 3)));
  int S = (int)lroundf(sqrtf((float)(out_size / 4)));
  float* outp = (float*)d_out;

  char* ws = (char*)d_ws;
  size_t off = 0;
  auto alloc = [&](size_t bytes) {
    void* p = ws + off;
    off = (off + bytes + 255) & ~(size_t)255;
    return p;
  };
  float* zinit = (float*)alloc(4);
  TriRec* rec = (TriRec*)alloc((size_t)MAXK * sizeof(TriRec));  // 128-aligned
  float4* bboxS = (float4*)alloc((size_t)MAXK * 16);
  float4* planeS = (float4*)alloc((size_t)MAXK * 16);
  TriUV* tuv = (TriUV*)alloc((size_t)K * sizeof(TriUV));

  int pblocks = 1 + (K + 255) / 256;
  prep_kernel<<<pblocks, 256, 0, stream>>>(verts, faces, uv, uvfaces, V, K,
                                           rec, bboxS, planeS, tuv, zinit);
  int tiles = (S >> 4) * (S >> 4);
  render_kernel<<<tiles, 512, 0, stream>>>(rec, bboxS, planeS, K, tuv, zinit,
                                           uvmap, T, outp, S);
}

// Round 12
// 27.742 us; speedup vs baseline: 1.2343x; 1.0260x over previous
//
#include <hip/hip_runtime.h>
#include <hip/hip_fp16.h>
#include <cmath>

// Match XLA/numpy: no FMA contraction anywhere (a*b - c*d must be two ops).
#pragma clang fp contract(off)

#define MAXK 2048  // next pow2 >= K (K=2000)

struct TriUV {
  float u0x, u0y, u1x, u1y;
  float u2x, u2y, pad0, pad1;
};

// All per-visit tri data in ONE 128B cache line (128-aligned).
struct __align__(128) TriRec {
  uint4 ap;     // fp16 edge coeffs packed
  float4 mt;    // M, fC, orig-as-float, 0
  float4 q0;    // t1x,t1y,dAy,dAx
  float4 q1;    // t2x,t2y,dBy,dBx
  float4 q2;    // t0x,t0y,dCy,dCx
  float4 q3;    // z0,z1,z2,w
  float4 pad0, pad1;  // -> 128B
};

__device__ __forceinline__ float h2f(unsigned v) {
  __half_raw r; r.x = (unsigned short)v;
  return __half2float(__half(r));
}
__device__ __forceinline__ unsigned f2h(float v) {
  return (unsigned)__half_as_ushort(__float2half(v));
}
__device__ __forceinline__ unsigned pkh(float lo, float hi) {
  return f2h(lo) | (f2h(hi) << 16);
}
// order-preserving float<->uint map (monotone for all finite floats)
__device__ __forceinline__ unsigned fmapu(float f) {
  unsigned b = __float_as_uint(f);
  return (b & 0x80000000u) ? ~b : (b | 0x80000000u);
}
__device__ __forceinline__ float funmap(unsigned m) {
  return __uint_as_float((m & 0x80000000u) ? (m ^ 0x80000000u) : ~m);
}

// jnp.linspace(-1, 1, n): start*(1-step) + stop*step with step=i/(n-1),
// endpoint concatenated exactly.
__device__ __forceinline__ float lin_at(int i, int n) {
#pragma clang fp contract(off)
  if (i == n - 1) return 1.0f;
  float step = (float)i / (float)(n - 1);
  return (-1.0f) * (1.0f - step) + 1.0f * step;
}

// PARALLEL single-pass prep: no global ordering needed (render re-sorts
// per-tile by its own gate; winner = order-independent lex-max of (z,orig)).
// slot == t identity. Invalid tris write a never-passing bbox only.
// Block 0: minz reduction. Blocks 1..: 256 tris each.
__global__ __launch_bounds__(256) void prep_kernel(
    const float* __restrict__ verts, const int* __restrict__ faces,
    const float* __restrict__ uv, const int* __restrict__ uvfaces, int V, int K,
    TriRec* __restrict__ rec, float4* __restrict__ bboxS,
    float4* __restrict__ planeS, TriUV* __restrict__ tuv,
    float* __restrict__ zinit) {
#pragma clang fp contract(off)
  __shared__ float smz[256];
  int tid = (int)threadIdx.x;
  int bid = (int)blockIdx.x;
  if (bid == 0) {
    float m = 3.402823466e38f;
    for (int i = tid; i < V; i += 256) m = fminf(m, verts[3 * i + 2]);
    smz[tid] = m;
    __syncthreads();
    for (int s2 = 128; s2 > 0; s2 >>= 1) {
      if (tid < s2) smz[tid] = fminf(smz[tid], smz[tid + s2]);
      __syncthreads();
    }
    if (tid == 0) *zinit = smz[0];
    return;
  }
  int t = (bid - 1) * 256 + tid;
  if (t >= K) return;
  int i0 = faces[3 * t + 0], i1 = faces[3 * t + 1], i2 = faces[3 * t + 2];
  float t0x = verts[3 * i0 + 0], t0y = verts[3 * i0 + 1], z0 = verts[3 * i0 + 2];
  float t1x = verts[3 * i1 + 0], t1y = verts[3 * i1 + 1], z1 = verts[3 * i1 + 2];
  float t2x = verts[3 * i2 + 0], t2y = verts[3 * i2 + 1], z2 = verts[3 * i2 + 2];
  int j0 = uvfaces[3 * t + 0], j1 = uvfaces[3 * t + 1], j2 = uvfaces[3 * t + 2];
  TriUV u;
  u.u0x = uv[2 * j0 + 0] * 2.0f - 1.0f;
  u.u0y = uv[2 * j0 + 1] * 2.0f - 1.0f;
  u.u1x = uv[2 * j1 + 0] * 2.0f - 1.0f;
  u.u1y = uv[2 * j1 + 1] * 2.0f - 1.0f;
  u.u2x = uv[2 * j2 + 0] * 2.0f - 1.0f;
  u.u2y = uv[2 * j2 + 1] * 2.0f - 1.0f;
  u.pad0 = 0.0f; u.pad1 = 0.0f;
  tuv[t] = u;
  // w == normal_z bitwise: valid & (w>=EPS) <=> w >= 1e-9f
  float w = (t1x - t0x) * (t2y - t0y) - (t1y - t0y) * (t2x - t0x);
  if (w < 1e-9f) {
    // never passes the tile bbox test; no other array is read for this t
    bboxS[t] = make_float4(3.0e38f, -3.0e38f, 3.0e38f, -3.0e38f);
    return;
  }
  float dAy = t0y - t1y, dAx = t0x - t1x;  // edge A (pAB), anchor t1
  float dBy = t1y - t2y, dBx = t1x - t2x;  // edge B (pCB), anchor t2
  float dCy = t2y - t0y, dCx = t2x - t0x;  // edge C (pCA), anchor t0
  bboxS[t] = make_float4(fminf(fminf(t0x, t1x), t2x),
                         fmaxf(fmaxf(t0x, t1x), t2x),
                         fminf(fminf(t0y, t1y), t2y),
                         fmaxf(fmaxf(t0y, t1y), t2y));
  // Approx edge form: p ~= px*d - py*e + f, f = b*e - a*d (anchor (a,b)).
  float fA = t1y * dAx - t1x * dAy;
  float fB = t2y * dBx - t2x * dBy;
  float fC = t0y * dCx - t0x * dCy;
  // Sound margin: fp16 quantization + fp32 fma + exact-expr rounding.
  float sA = fabsf(dAy) + fabsf(dAx) + fabsf(fA);
  float sB = fabsf(dBy) + fabsf(dBx) + fabsf(fB);
  float sC = fabsf(dCy) + fabsf(dCx) + fabsf(fC);
  float M = fmaxf(fmaxf(sA, sB), sC) * 9.766e-4f + 1e-4f;
  TriRec r;
  r.ap = make_uint4(pkh(dAy, dAx), pkh(fA, dBy), pkh(dBx, fB), pkh(dCy, dCx));
  r.mt = make_float4(M, fC, __int_as_float(t), 0.0f);
  r.q0 = make_float4(t1x, t1y, dAy, dAx);
  r.q1 = make_float4(t2x, t2y, dBy, dBx);
  r.q2 = make_float4(t0x, t0y, dCy, dCx);
  r.q3 = make_float4(z0, z1, z2, w);
  r.pad0 = make_float4(0.f, 0.f, 0.f, 0.f);
  r.pad1 = make_float4(0.f, 0.f, 0.f, 0.f);
  rec[t] = r;
  // z plane: z(x,y) = (z0*pCB + z1*pCA + z2*pAB)/w is affine in (x,y).
  // pXX(0,0) = fB/fC/fA; d(pCB)/dx = dBy, d(pCA)/dx = dCy, d(pAB)/dx = dAy.
  float zmx = fmaxf(fmaxf(z0, z1), z2);
  float gatef = zmx + 1e-3f + 1e-4f / w;  // exact global gate (strict UB)
  float gx = (z0 * dBy + z1 * dCy + z2 * dAy) / w;
  float gy = -(z0 * dBx + z1 * dCx + z2 * dAx) / w;
  float cc = (z0 * fB + z1 * fC + z2 * fA) / w;
  // margin: coefficient fp error (magnitude-scaled) + render-side eval
  // rounding + established inner-z error (1e-3 + 1e-4/w) + abs cushion.
  float mm = (fabsf(z0 * fB) + fabsf(z1 * fC) + fabsf(z2 * fA) +
              fabsf(z0 * dBy) + fabsf(z1 * dCy) + fabsf(z2 * dAy) +
              fabsf(z0 * dBx) + fabsf(z1 * dCx) + fabsf(z2 * dAx)) *
                 (2e-6f / w) +
             1e-3f + 1e-4f / w + 1e-4f;
  planeS[t] = make_float4(gx, gy, cc + mm, gatef);
}

// 16x16 tile, 512 threads = 8 waves, 4 BLOCKS/CU (single-round residency —
// R10 structure, best measured). Wave wv: substream s=wv>>2 in {0,1},
// quadrant q=wv&3 (lane ln -> pixel q*64+ln; 2 waves per pixel).
// Per-pixel winner = 64-bit LDS atomicMax of (map(z)<<32 | orig+1): exact
// lex-max of (z, orig). Phase 0 sorts bbox-survivors by
//   tg = min(globalGate, planeZmax over (bbox ∩ tile) + margin)
// — the plane UB is taken over the BBOX∩TILE intersection rect (tighter
// than the whole tile for corner-clipping tris; still a superset of the
// triangle's in-tile region, so the gate remains a sound upper bound and
// pruning stays provable-skip: winner math bitwise unchanged).
// Phase 1 body is byte-for-byte R6's scalar loop, stride 2.
__global__ __launch_bounds__(512) void render_kernel(
    const TriRec* __restrict__ rec, const float4* __restrict__ bboxS,
    const float4* __restrict__ planeS, int N, const TriUV* __restrict__ tuv,
    const float* __restrict__ zinitp, const float* __restrict__ uvmap, int T,
    float* __restrict__ out, int S) {
#pragma clang fp contract(off)
  __shared__ uint4 s_g[MAXK];                   // 32KB (em, tg, idx, 0)
  __shared__ unsigned long long s_key[256];     // 2KB winner (z,orig+1)
  __shared__ unsigned s_zu[256];                // 1KB pruning max (mapped z)
  __shared__ unsigned s_hist[256];              // 1KB
  __shared__ int s_cur[256];                    // 1KB
  __shared__ unsigned s_wsum[4];                // -> ~37KB total (4/CU fits)

  int tid = (int)threadIdx.x;
  int wv = tid >> 6, ln = tid & 63;
  int s = wv >> 2, q = wv & 3;   // s in {0,1}, q in {0..3}
  int pix = (q << 6) + ln;
  int tilesX = S >> 4;
  int tileX = (int)blockIdx.x % tilesX;
  int tileY = (int)blockIdx.x / tilesX;
  int j = (tileX << 4) + (pix & 15);
  int i = (tileY << 4) + (pix >> 4);
  // pts[i][j] = (lin[j], lin[S-1-i])  (rot90 of meshgrid)
  float px = lin_at(j, S);
  float py = lin_at(S - 1 - i, S);
  float pxlo = lin_at(tileX << 4, S);
  float pxhi = lin_at((tileX << 4) + 15, S);
  float pylo = lin_at(S - 1 - ((tileY << 4) + 15), S);
  float pyhi = lin_at(S - 1 - (tileY << 4), S);

  float zinit = *zinitp;
  unsigned zinit_m = fmapu(zinit);
  if (tid < 256) {
    s_zu[tid] = zinit_m;
    s_key[tid] = ((unsigned long long)zinit_m << 32);  // orig+1 = 0 -> none
    s_hist[tid] = 0u;
  }
  volatile unsigned* vzu = s_zu;
  __syncthreads();

  // ---- Phase 0: bbox cull + bbox∩tile plane gate + 256-bucket sort ----
  bool kk[4] = {false, false, false, false};
  int bb4[4] = {0, 0, 0, 0};
  unsigned gg[4] = {0, 0, 0, 0};
#pragma unroll
  for (int c = 0; c < 4; ++c) {
    int t = tid + (c << 9);  // tid + c*512
    if (t < N) {
      float4 bb = bboxS[t];  // xmin,xmax,ymin,ymax
      if (bb.x <= pxhi && bb.y >= pxlo && bb.z <= pyhi && bb.w >= pylo) {
        float4 pl = planeS[t];  // gx, gy, c+margin, globalGate
        // intersection rect (nonempty: bbox test passed)
        float xlo2 = fmaxf(pxlo, bb.x), xhi2 = fminf(pxhi, bb.y);
        float ylo2 = fmaxf(pylo, bb.z), yhi2 = fminf(pyhi, bb.w);
        float ub = pl.z + fmaxf(pl.x * xlo2, pl.x * xhi2) +
                   fmaxf(pl.y * ylo2, pl.y * yhi2);
        float tg = fminf(pl.w, ub);
        kk[c] = true;
        bb4[c] = min(max((int)((4.0f - tg) * 32.0f), 0), 255);
        gg[c] = fmapu(tg);
      }
    }
  }
#pragma unroll
  for (int c = 0; c < 4; ++c)
    if (kk[c]) atomicAdd(&s_hist[bb4[c]], 1u);
  __syncthreads();
  // 256-bin inclusive scan: 4 waves shuffle-scan 64 bins each + fixup.
  unsigned hx = 0, hinc = 0;
  if (tid < 256) {
    hx = s_hist[tid];
    unsigned v = hx;
#pragma unroll
    for (int d = 1; d < 64; d <<= 1) {
      unsigned tv = __shfl_up(v, d, 64);
      if (ln >= d) v += tv;
    }
    if (ln == 63) s_wsum[wv] = v;
    hinc = v;
  }
  __syncthreads();
  if (tid < 256) {
    unsigned add = 0;
    for (int w2 = 0; w2 < wv; ++w2) add += s_wsum[w2];
    hinc += add;
    s_hist[tid] = hinc;                 // inclusive totals (nk at bin 255)
    s_cur[tid] = (int)(hinc - hx);      // exclusive start cursor
  }
  __syncthreads();
  int nk = (int)s_hist[255];
#pragma unroll
  for (int c = 0; c < 4; ++c) {
    if (kk[c]) {
      int sl = atomicAdd(&s_cur[bb4[c]], 1);
      float ef =
          (bb4[c] == 0) ? 3.402823466e38f : (4.0f - (float)bb4[c] * 0.03125f);
      s_g[sl] = make_uint4(fmapu(ef), gg[c], (unsigned)(tid + (c << 9)), 0u);
    }
  }
  __syncthreads();

  // ---- Phase 1: scalar parity-2 scan (R6 body), shared-z pruning ----
  for (int a = s; a < nk; a += 2) {
    uint4 g = s_g[a];        // one ds_read_b128: em, tg, idx
    unsigned zb = vzu[pix];  // fresh shared max (volatile)
    // edges monotone along substream: all lanes provably finished -> stop
    if (__all(g.x < zb)) break;
    if (g.y >= zb) {  // provable-skip pretest (tg>=zb implies em>=zb)
      const TriRec* r = &rec[g.z];  // whole visit = one 128B line
      uint4 ap = r->ap;
      float4 mt = r->mt;
      float M = mt.x, fC = mt.y;
      // approx edges (fp16 coeffs, fp32 fma); |approx-exact| <= M
      float aA = fmaf(px, h2f(ap.x & 0xffffu),
                      fmaf(-py, h2f(ap.x >> 16), h2f(ap.y & 0xffffu)));
      float aB = fmaf(px, h2f(ap.y >> 16),
                      fmaf(-py, h2f(ap.z & 0xffffu), h2f(ap.z >> 16)));
      float aC = fmaf(px, h2f(ap.w & 0xffffu),
                      fmaf(-py, h2f(ap.w >> 16), fC));
      if (fminf(fminf(aA, aB), aC) > -M) {  // not provably outside
        float4 q0 = r->q0, q1 = r->q1, q2 = r->q2;
        float pAB = (px - q0.x) * q0.z - (py - q0.y) * q0.w;
        float pCB = (px - q1.x) * q1.z - (py - q1.y) * q1.w;
        float pCA = (px - q2.x) * q2.z - (py - q2.y) * q2.w;
        if (pAB > 0.0f && pCB > 0.0f && pCA > 0.0f) {
          float4 q3 = r->q3;
          float w = q3.w;
          float bzf = funmap(vzu[pix]);
          // scaled z pregate: skip divides when provably losing
          float zs = (pCB * q3.x + pCA * q3.y) + ((w - pCB) - pCA) * q3.z;
          if (w < 1e-3f || zs >= (bzf - 1e-3f) * w) {
            float w1 = pCB / w;  // IEEE div, bitwise == reference
            float w2 = pCA / w;
            float w3 = (1.0f - w1) - w2;
            float z = (w1 * q3.x + w2 * q3.y) + w3 * q3.z;
            int o = __float_as_int(mt.z);
            unsigned zm = fmapu(z);
            unsigned long long key =
                ((unsigned long long)zm << 32) | (unsigned)(o + 1);
            atomicMax(&s_key[pix], key);
            atomicMax(&s_zu[pix], zm);
          }
        }
      }
    }
  }
  __syncthreads();

  // ---- Epilogue (tid<256, pix==tid): unpack winner, recompute w1/w2 ----
  if (tid < 256) {
    unsigned long long key = s_key[tid];
    unsigned oP1 = (unsigned)(key & 0xFFFFFFFFULL);
    float o0 = 0.0f, o1 = 0.0f, o2 = 0.0f, o3 = 0.0f;
    if (oP1 != 0) {
      int o = (int)oP1 - 1;  // slot == orig (identity)
      const TriRec* r = &rec[o];
      float4 q1 = r->q1, q2 = r->q2, q3 = r->q3;
      float pCB = (px - q1.x) * q1.z - (py - q1.y) * q1.w;
      float pCA = (px - q2.x) * q2.z - (py - q2.y) * q2.w;
      float w1 = pCB / q3.w;  // bitwise == inner-loop values
      float w2 = pCA / q3.w;
      float w3 = (1.0f - w1) - w2;
      TriUV u = tuv[o];
      float x = (w1 * u.u0x + w2 * u.u1x) + w3 * u.u2x;
      float y = (w1 * u.u0y + w2 * u.u1y) + w3 * u.u2y;
      float WH = (float)(T - 1);
      float fx = ((x + 1.0f) * WH) * 0.5f;
      float fy = ((y + 1.0f) * WH) * 0.5f;
      float ix0 = floorf(fx), iy0 = floorf(fy);
      float ix1 = ix0 + 1.0f, iy1 = iy0 + 1.0f;
      float wx1 = fx - ix0, wx0 = 1.0f - wx1;
      float wy1 = fy - iy0, wy0 = 1.0f - wy1;
      float w00 = wy0 * wx0, w01 = wy0 * wx1;
      float w10 = wy1 * wx0, w11 = wy1 * wx1;
      bool bx0 = (ix0 >= 0.0f) && (ix0 <= WH);
      bool bx1 = (ix1 >= 0.0f) && (ix1 <= WH);
      bool by0 = (iy0 >= 0.0f) && (iy0 <= WH);
      bool by1 = (iy1 >= 0.0f) && (iy1 <= WH);
      float m00 = (by0 && bx0) ? 1.0f : 0.0f;
      float m01 = (by0 && bx1) ? 1.0f : 0.0f;
      float m10 = (by1 && bx0) ? 1.0f : 0.0f;
      float m11 = (by1 && bx1) ? 1.0f : 0.0f;
      int cx0 = (int)fminf(fmaxf(ix0, 0.0f), WH);
      int cx1 = (int)fminf(fmaxf(ix1, 0.0f), WH);
      int cy0 = (int)fminf(fmaxf(iy0, 0.0f), WH);
      int cy1 = (int)fminf(fmaxf(iy1, 0.0f), WH);
      int TT = T * T;
      int i00 = cy0 * T + cx0, i01 = cy0 * T + cx1;
      int i10 = cy1 * T + cx0, i11 = cy1 * T + cx1;
      {
        const float* img = uvmap;
        float v00 = img[i00] * m00, v01 = img[i01] * m01;
        float v10 = img[i10] * m10, v11 = img[i11] * m11;
        o0 = ((v00 * w00 + v01 * w01) + v10 * w10) + v11 * w11;
      }
      {
        const float* img = uvmap + TT;
        float v00 = img[i00] * m00, v01 = img[i01] * m01;
        float v10 = img[i10] * m10, v11 = img[i11] * m11;
        o1 = ((v00 * w00 + v01 * w01) + v10 * w10) + v11 * w11;
      }
      {
        const float* img = uvmap + 2 * TT;
        float v00 = img[i00] * m00, v01 = img[i01] * m01;
        float v10 = img[i10] * m10, v11 = img[i11] * m11;
        o2 = ((v00 * w00 + v01 * w01) + v10 * w10) + v11 * w11;
      }
      o3 = 1.0f;
    }
    int p = i * S + j;  // pix == tid: (i,j) are this pixel's coords
    int SS = S * S;
    out[p] = o0;
    out[SS + p] = o1;
    out[2 * SS + p] = o2;
    out[3 * SS + p] = o3;
  }
}

extern "C" void kernel_launch(void* const* d_in, const int* in_sizes, int n_in,
                              void* d_out, int out_size, void* d_ws,
                              size_t ws_size, hipStream_t stream) {
  const float* verts = (const float*)d_in[0];
  const int* faces = (const int*)d_in[1];
  const float* uv = (const float*)d_in[2];
  const int* uvfaces = (const int*)d_in[3];
  const float* uvmap = (const float*)d_in[4];
  int V = in_sizes[0] / 3;
  int K = in_sizes[1] / 3;
  int T = (int)lroundf(sqrtf((float)(in_sizes[4] / 3)));
  int S = (int)lroundf(sqrtf((float)(out_size / 4)));
  float* outp = (float*)d_out;

  char* ws = (char*)d_ws;
  size_t off = 0;
  auto alloc = [&](size_t bytes) {
    void* p = ws + off;
    off = (off + bytes + 255) & ~(size_t)255;
    return p;
  };
  float* zinit = (float*)alloc(4);
  TriRec* rec = (TriRec*)alloc((size_t)MAXK * sizeof(TriRec));  // 128-aligned
  float4* bboxS = (float4*)alloc((size_t)MAXK * 16);
  float4* planeS = (float4*)alloc((size_t)MAXK * 16);
  TriUV* tuv = (TriUV*)alloc((size_t)K * sizeof(TriUV));

  int pblocks = 1 + (K + 255) / 256;
  prep_kernel<<<pblocks, 256, 0, stream>>>(verts, faces, uv, uvfaces, V, K,
                                           rec, bboxS, planeS, tuv, zinit);
  int tiles = (S >> 4) * (S >> 4);
  render_kernel<<<tiles, 512, 0, stream>>>(rec, bboxS, planeS, K, tuv, zinit,
                                           uvmap, T, outp, S);
}

// Round 13
// 27.649 us; speedup vs baseline: 1.2385x; 1.0033x over previous
//
#include <hip/hip_runtime.h>
#include <hip/hip_fp16.h>
#include <cmath>

// Match XLA/numpy: no FMA contraction anywhere (a*b - c*d must be two ops).
#pragma clang fp contract(off)

#define MAXK 2048  // next pow2 >= K (K=2000)

struct TriUV {
  float u0x, u0y, u1x, u1y;
  float u2x, u2y, pad0, pad1;
};

// All per-visit tri data in ONE 64B half-line (64-aligned): exact edge
// forms + z. (fp16 approx pretest removed in R12 — with the AoS record the
// exact edges cost no more VALU and come from the same cache line.)
struct __align__(64) TriRec {
  float4 q0;    // t1x,t1y,dAy,dAx
  float4 q1;    // t2x,t2y,dBy,dBx
  float4 q2;    // t0x,t0y,dCy,dCx
  float4 q3;    // z0,z1,z2,w
};

// order-preserving float<->uint map (monotone for all finite floats)
__device__ __forceinline__ unsigned fmapu(float f) {
  unsigned b = __float_as_uint(f);
  return (b & 0x80000000u) ? ~b : (b | 0x80000000u);
}
__device__ __forceinline__ float funmap(unsigned m) {
  return __uint_as_float((m & 0x80000000u) ? (m ^ 0x80000000u) : ~m);
}

// jnp.linspace(-1, 1, n): start*(1-step) + stop*step with step=i/(n-1),
// endpoint concatenated exactly.
__device__ __forceinline__ float lin_at(int i, int n) {
#pragma clang fp contract(off)
  if (i == n - 1) return 1.0f;
  float step = (float)i / (float)(n - 1);
  return (-1.0f) * (1.0f - step) + 1.0f * step;
}

// PARALLEL single-pass prep: no global ordering needed (render re-sorts
// per-tile by its own gate; winner = order-independent lex-max of (z,orig)).
// slot == t identity. Invalid tris write a never-passing bbox only.
// Block 0: minz reduction. Blocks 1..: 256 tris each.
__global__ __launch_bounds__(256) void prep_kernel(
    const float* __restrict__ verts, const int* __restrict__ faces,
    const float* __restrict__ uv, const int* __restrict__ uvfaces, int V, int K,
    TriRec* __restrict__ rec, float4* __restrict__ bboxS,
    float4* __restrict__ planeS, TriUV* __restrict__ tuv,
    float* __restrict__ zinit) {
#pragma clang fp contract(off)
  __shared__ float smz[256];
  int tid = (int)threadIdx.x;
  int bid = (int)blockIdx.x;
  if (bid == 0) {
    float m = 3.402823466e38f;
    for (int i = tid; i < V; i += 256) m = fminf(m, verts[3 * i + 2]);
    smz[tid] = m;
    __syncthreads();
    for (int s2 = 128; s2 > 0; s2 >>= 1) {
      if (tid < s2) smz[tid] = fminf(smz[tid], smz[tid + s2]);
      __syncthreads();
    }
    if (tid == 0) *zinit = smz[0];
    return;
  }
  int t = (bid - 1) * 256 + tid;
  if (t >= K) return;
  int i0 = faces[3 * t + 0], i1 = faces[3 * t + 1], i2 = faces[3 * t + 2];
  float t0x = verts[3 * i0 + 0], t0y = verts[3 * i0 + 1], z0 = verts[3 * i0 + 2];
  float t1x = verts[3 * i1 + 0], t1y = verts[3 * i1 + 1], z1 = verts[3 * i1 + 2];
  float t2x = verts[3 * i2 + 0], t2y = verts[3 * i2 + 1], z2 = verts[3 * i2 + 2];
  int j0 = uvfaces[3 * t + 0], j1 = uvfaces[3 * t + 1], j2 = uvfaces[3 * t + 2];
  TriUV u;
  u.u0x = uv[2 * j0 + 0] * 2.0f - 1.0f;
  u.u0y = uv[2 * j0 + 1] * 2.0f - 1.0f;
  u.u1x = uv[2 * j1 + 0] * 2.0f - 1.0f;
  u.u1y = uv[2 * j1 + 1] * 2.0f - 1.0f;
  u.u2x = uv[2 * j2 + 0] * 2.0f - 1.0f;
  u.u2y = uv[2 * j2 + 1] * 2.0f - 1.0f;
  u.pad0 = 0.0f; u.pad1 = 0.0f;
  tuv[t] = u;
  // w == normal_z bitwise: valid & (w>=EPS) <=> w >= 1e-9f
  float w = (t1x - t0x) * (t2y - t0y) - (t1y - t0y) * (t2x - t0x);
  if (w < 1e-9f) {
    // never passes the tile bbox test; no other array is read for this t
    bboxS[t] = make_float4(3.0e38f, -3.0e38f, 3.0e38f, -3.0e38f);
    return;
  }
  float dAy = t0y - t1y, dAx = t0x - t1x;  // edge A (pAB), anchor t1
  float dBy = t1y - t2y, dBx = t1x - t2x;  // edge B (pCB), anchor t2
  float dCy = t2y - t0y, dCx = t2x - t0x;  // edge C (pCA), anchor t0
  bboxS[t] = make_float4(fminf(fminf(t0x, t1x), t2x),
                         fmaxf(fmaxf(t0x, t1x), t2x),
                         fminf(fminf(t0y, t1y), t2y),
                         fmaxf(fmaxf(t0y, t1y), t2y));
  TriRec r;
  r.q0 = make_float4(t1x, t1y, dAy, dAx);
  r.q1 = make_float4(t2x, t2y, dBy, dBx);
  r.q2 = make_float4(t0x, t0y, dCy, dCx);
  r.q3 = make_float4(z0, z1, z2, w);
  rec[t] = r;
  // Edge constants for the z-plane: f = b*e - a*d (anchor (a,b)).
  float fA = t1y * dAx - t1x * dAy;
  float fB = t2y * dBx - t2x * dBy;
  float fC = t0y * dCx - t0x * dCy;
  // z plane: z(x,y) = (z0*pCB + z1*pCA + z2*pAB)/w is affine in (x,y).
  // pXX(0,0) = fB/fC/fA; d(pCB)/dx = dBy, d(pCA)/dx = dCy, d(pAB)/dx = dAy.
  float zmx = fmaxf(fmaxf(z0, z1), z2);
  float gatef = zmx + 1e-3f + 1e-4f / w;  // exact global gate (strict UB)
  float gx = (z0 * dBy + z1 * dCy + z2 * dAy) / w;
  float gy = -(z0 * dBx + z1 * dCx + z2 * dAx) / w;
  float cc = (z0 * fB + z1 * fC + z2 * fA) / w;
  // margin: coefficient fp error (magnitude-scaled) + render-side eval
  // rounding + established inner-z error (1e-3 + 1e-4/w) + abs cushion.
  float mm = (fabsf(z0 * fB) + fabsf(z1 * fC) + fabsf(z2 * fA) +
              fabsf(z0 * dBy) + fabsf(z1 * dCy) + fabsf(z2 * dAy) +
              fabsf(z0 * dBx) + fabsf(z1 * dCx) + fabsf(z2 * dAx)) *
                 (2e-6f / w) +
             1e-3f + 1e-4f / w + 1e-4f;
  planeS[t] = make_float4(gx, gy, cc + mm, gatef);
}

// 16x16 tile, 512 threads = 8 waves, 4 BLOCKS/CU (single-round residency —
// R10 structure, best measured). Wave wv: substream s=wv>>2 in {0,1},
// quadrant q=wv&3 (lane ln -> pixel q*64+ln; 2 waves per pixel).
// Per-pixel winner = 64-bit LDS atomicMax of (map(z)<<32 | orig+1): exact
// lex-max of (z, orig). Phase 0 sorts bbox-survivors by
//   tg = min(globalGate, planeZmax over (bbox ∩ tile) + margin)  (R11).
// Phase 1: R6 scalar loop, stride 2; deep visit = ONE 64B record, exact
// edge tests directly (approx fp16 pretest removed — same winner set,
// less VALU per visit).
__global__ __launch_bounds__(512) void render_kernel(
    const TriRec* __restrict__ rec, const float4* __restrict__ bboxS,
    const float4* __restrict__ planeS, int N, const TriUV* __restrict__ tuv,
    const float* __restrict__ zinitp, const float* __restrict__ uvmap, int T,
    float* __restrict__ out, int S) {
#pragma clang fp contract(off)
  __shared__ uint4 s_g[MAXK];                   // 32KB (em, tg, idx, 0)
  __shared__ unsigned long long s_key[256];     // 2KB winner (z,orig+1)
  __shared__ unsigned s_zu[256];                // 1KB pruning max (mapped z)
  __shared__ unsigned s_hist[256];              // 1KB
  __shared__ int s_cur[256];                    // 1KB
  __shared__ unsigned s_wsum[4];                // -> ~37KB total (4/CU fits)

  int tid = (int)threadIdx.x;
  int wv = tid >> 6, ln = tid & 63;
  int s = wv >> 2, q = wv & 3;   // s in {0,1}, q in {0..3}
  int pix = (q << 6) + ln;
  int tilesX = S >> 4;
  int tileX = (int)blockIdx.x % tilesX;
  int tileY = (int)blockIdx.x / tilesX;
  int j = (tileX << 4) + (pix & 15);
  int i = (tileY << 4) + (pix >> 4);
  // pts[i][j] = (lin[j], lin[S-1-i])  (rot90 of meshgrid)
  float px = lin_at(j, S);
  float py = lin_at(S - 1 - i, S);
  float pxlo = lin_at(tileX << 4, S);
  float pxhi = lin_at((tileX << 4) + 15, S);
  float pylo = lin_at(S - 1 - ((tileY << 4) + 15), S);
  float pyhi = lin_at(S - 1 - (tileY << 4), S);

  float zinit = *zinitp;
  unsigned zinit_m = fmapu(zinit);
  if (tid < 256) {
    s_zu[tid] = zinit_m;
    s_key[tid] = ((unsigned long long)zinit_m << 32);  // orig+1 = 0 -> none
    s_hist[tid] = 0u;
  }
  volatile unsigned* vzu = s_zu;
  __syncthreads();

  // ---- Phase 0: bbox cull + bbox∩tile plane gate + 256-bucket sort ----
  bool kk[4] = {false, false, false, false};
  int bb4[4] = {0, 0, 0, 0};
  unsigned gg[4] = {0, 0, 0, 0};
#pragma unroll
  for (int c = 0; c < 4; ++c) {
    int t = tid + (c << 9);  // tid + c*512
    if (t < N) {
      float4 bb = bboxS[t];  // xmin,xmax,ymin,ymax
      if (bb.x <= pxhi && bb.y >= pxlo && bb.z <= pyhi && bb.w >= pylo) {
        float4 pl = planeS[t];  // gx, gy, c+margin, globalGate
        // intersection rect (nonempty: bbox test passed)
        float xlo2 = fmaxf(pxlo, bb.x), xhi2 = fminf(pxhi, bb.y);
        float ylo2 = fmaxf(pylo, bb.z), yhi2 = fminf(pyhi, bb.w);
        float ub = pl.z + fmaxf(pl.x * xlo2, pl.x * xhi2) +
                   fmaxf(pl.y * ylo2, pl.y * yhi2);
        float tg = fminf(pl.w, ub);
        kk[c] = true;
        bb4[c] = min(max((int)((4.0f - tg) * 32.0f), 0), 255);
        gg[c] = fmapu(tg);
      }
    }
  }
#pragma unroll
  for (int c = 0; c < 4; ++c)
    if (kk[c]) atomicAdd(&s_hist[bb4[c]], 1u);
  __syncthreads();
  // 256-bin inclusive scan: 4 waves shuffle-scan 64 bins each + fixup.
  unsigned hx = 0, hinc = 0;
  if (tid < 256) {
    hx = s_hist[tid];
    unsigned v = hx;
#pragma unroll
    for (int d = 1; d < 64; d <<= 1) {
      unsigned tv = __shfl_up(v, d, 64);
      if (ln >= d) v += tv;
    }
    if (ln == 63) s_wsum[wv] = v;
    hinc = v;
  }
  __syncthreads();
  if (tid < 256) {
    unsigned add = 0;
    for (int w2 = 0; w2 < wv; ++w2) add += s_wsum[w2];
    hinc += add;
    s_hist[tid] = hinc;                 // inclusive totals (nk at bin 255)
    s_cur[tid] = (int)(hinc - hx);      // exclusive start cursor
  }
  __syncthreads();
  int nk = (int)s_hist[255];
#pragma unroll
  for (int c = 0; c < 4; ++c) {
    if (kk[c]) {
      int sl = atomicAdd(&s_cur[bb4[c]], 1);
      float ef =
          (bb4[c] == 0) ? 3.402823466e38f : (4.0f - (float)bb4[c] * 0.03125f);
      s_g[sl] = make_uint4(fmapu(ef), gg[c], (unsigned)(tid + (c << 9)), 0u);
    }
  }
  __syncthreads();

  // ---- Phase 1: scalar parity-2 scan (R6 body, exact-edge visits) ----
  for (int a = s; a < nk; a += 2) {
    uint4 g = s_g[a];        // one ds_read_b128: em, tg, idx
    unsigned zb = vzu[pix];  // fresh shared max (volatile)
    // edges monotone along substream: all lanes provably finished -> stop
    if (__all(g.x < zb)) break;
    if (g.y >= zb) {  // provable-skip pretest (tg>=zb implies em>=zb)
      const TriRec* r = &rec[g.z];  // whole visit = one 64B half-line
      float4 q0 = r->q0, q1 = r->q1, q2 = r->q2;
      float pAB = (px - q0.x) * q0.z - (py - q0.y) * q0.w;
      float pCB = (px - q1.x) * q1.z - (py - q1.y) * q1.w;
      float pCA = (px - q2.x) * q2.z - (py - q2.y) * q2.w;
      if (pAB > 0.0f && pCB > 0.0f && pCA > 0.0f) {
        float4 q3 = r->q3;
        float w = q3.w;
        float bzf = funmap(vzu[pix]);
        // scaled z pregate: skip divides when provably losing
        float zs = (pCB * q3.x + pCA * q3.y) + ((w - pCB) - pCA) * q3.z;
        if (w < 1e-3f || zs >= (bzf - 1e-3f) * w) {
          float w1 = pCB / w;  // IEEE div, bitwise == reference
          float w2 = pCA / w;
          float w3 = (1.0f - w1) - w2;
          float z = (w1 * q3.x + w2 * q3.y) + w3 * q3.z;
          int o = (int)g.z;  // slot == orig (identity)
          unsigned zm = fmapu(z);
          unsigned long long key =
              ((unsigned long long)zm << 32) | (unsigned)(o + 1);
          atomicMax(&s_key[pix], key);
          atomicMax(&s_zu[pix], zm);
        }
      }
    }
  }
  __syncthreads();

  // ---- Epilogue (tid<256, pix==tid): unpack winner, recompute w1/w2 ----
  if (tid < 256) {
    unsigned long long key = s_key[tid];
    unsigned oP1 = (unsigned)(key & 0xFFFFFFFFULL);
    float o0 = 0.0f, o1 = 0.0f, o2 = 0.0f, o3 = 0.0f;
    if (oP1 != 0) {
      int o = (int)oP1 - 1;  // slot == orig (identity)
      const TriRec* r = &rec[o];
      float4 q1 = r->q1, q2 = r->q2, q3 = r->q3;
      float pCB = (px - q1.x) * q1.z - (py - q1.y) * q1.w;
      float pCA = (px - q2.x) * q2.z - (py - q2.y) * q2.w;
      float w1 = pCB / q3.w;  // bitwise == inner-loop values
      float w2 = pCA / q3.w;
      float w3 = (1.0f - w1) - w2;
      TriUV u = tuv[o];
      float x = (w1 * u.u0x + w2 * u.u1x) + w3 * u.u2x;
      float y = (w1 * u.u0y + w2 * u.u1y) + w3 * u.u2y;
      float WH = (float)(T - 1);
      float fx = ((x + 1.0f) * WH) * 0.5f;
      float fy = ((y + 1.0f) * WH) * 0.5f;
      float ix0 = floorf(fx), iy0 = floorf(fy);
      float ix1 = ix0 + 1.0f, iy1 = iy0 + 1.0f;
      float wx1 = fx - ix0, wx0 = 1.0f - wx1;
      float wy1 = fy - iy0, wy0 = 1.0f - wy1;
      float w00 = wy0 * wx0, w01 = wy0 * wx1;
      float w10 = wy1 * wx0, w11 = wy1 * wx1;
      bool bx0 = (ix0 >= 0.0f) && (ix0 <= WH);
      bool bx1 = (ix1 >= 0.0f) && (ix1 <= WH);
      bool by0 = (iy0 >= 0.0f) && (iy0 <= WH);
      bool by1 = (iy1 >= 0.0f) && (iy1 <= WH);
      float m00 = (by0 && bx0) ? 1.0f : 0.0f;
      float m01 = (by0 && bx1) ? 1.0f : 0.0f;
      float m10 = (by1 && bx0) ? 1.0f : 0.0f;
      float m11 = (by1 && bx1) ? 1.0f : 0.0f;
      int cx0 = (int)fminf(fmaxf(ix0, 0.0f), WH);
      int cx1 = (int)fminf(fmaxf(ix1, 0.0f), WH);
      int cy0 = (int)fminf(fmaxf(iy0, 0.0f), WH);
      int cy1 = (int)fminf(fmaxf(iy1, 0.0f), WH);
      int TT = T * T;
      int i00 = cy0 * T + cx0, i01 = cy0 * T + cx1;
      int i10 = cy1 * T + cx0, i11 = cy1 * T + cx1;
      {
        const float* img = uvmap;
        float v00 = img[i00] * m00, v01 = img[i01] * m01;
        float v10 = img[i10] * m10, v11 = img[i11] * m11;
        o0 = ((v00 * w00 + v01 * w01) + v10 * w10) + v11 * w11;
      }
      {
        const float* img = uvmap + TT;
        float v00 = img[i00] * m00, v01 = img[i01] * m01;
        float v10 = img[i10] * m10, v11 = img[i11] * m11;
        o1 = ((v00 * w00 + v01 * w01) + v10 * w10) + v11 * w11;
      }
      {
        const float* img = uvmap + 2 * TT;
        float v00 = img[i00] * m00, v01 = img[i01] * m01;
        float v10 = img[i10] * m10, v11 = img[i11] * m11;
        o2 = ((v00 * w00 + v01 * w01) + v10 * w10) + v11 * w11;
      }
      o3 = 1.0f;
    }
    int p = i * S + j;  // pix == tid: (i,j) are this pixel's coords
    int SS = S * S;
    out[p] = o0;
    out[SS + p] = o1;
    out[2 * SS + p] = o2;
    out[3 * SS + p] = o3;
  }
}

extern "C" void kernel_launch(void* const* d_in, const int* in_sizes, int n_in,
                              void* d_out, int out_size, void* d_ws,
                              size_t ws_size, hipStream_t stream) {
  const float* verts = (const float*)d_in[0];
  const int* faces = (const int*)d_in[1];
  const float* uv = (const float*)d_in[2];
  const int* uvfaces = (const int*)d_in[3];
  const float* uvmap = (const float*)d_in[4];
  int V = in_sizes[0] / 3;
  int K = in_sizes[1] / 3;
  int T = (int)lroundf(sqrtf((float)(in_sizes[4] / 3)));
  int S = (int)lroundf(sqrtf((float)(out_size / 4)));
  float* outp = (float*)d_out;

  char* ws = (char*)d_ws;
  size_t off = 0;
  auto alloc = [&](size_t bytes) {
    void* p = ws + off;
    off = (off + bytes + 255) & ~(size_t)255;
    return p;
  };
  float* zinit = (float*)alloc(4);
  TriRec* rec = (TriRec*)alloc((size_t)MAXK * sizeof(TriRec));  // 64-aligned
  float4* bboxS = (float4*)alloc((size_t)MAXK * 16);
  float4* planeS = (float4*)alloc((size_t)MAXK * 16);
  TriUV* tuv = (TriUV*)alloc((size_t)K * sizeof(TriUV));

  int pblocks = 1 + (K + 255) / 256;
  prep_kernel<<<pblocks, 256, 0, stream>>>(verts, faces, uv, uvfaces, V, K,
                                           rec, bboxS, planeS, tuv, zinit);
  int tiles = (S >> 4) * (S >> 4);
  render_kernel<<<tiles, 512, 0, stream>>>(rec, bboxS, planeS, K, tuv, zinit,
                                           uvmap, T, outp, S);
}